// Round 4
// baseline (635.000 us; speedup 1.0000x reference)
//
#include <hip/hip_runtime.h>
#include <hip/hip_fp16.h>

#define HDIM 64
#define NEG_SLOPE 0.01f
#define CAPB 8192      // bucketed[] region per 128-node bucket
#define BCAP 6144      // LDS staging capacity in k_csr

static __device__ __forceinline__ float h_lo(unsigned d) {
    return __half2float(__ushort_as_half((unsigned short)(d & 0xffffu)));
}
static __device__ __forceinline__ float h_hi(unsigned d) {
    return __half2float(__ushort_as_half((unsigned short)(d >> 16)));
}
static __device__ __forceinline__ unsigned packh(float a, float b) {
    unsigned short ra = __half_as_ushort(__float2half(a));
    unsigned short rb = __half_as_ushort(__float2half(b));
    return ((unsigned)rb << 16) | (unsigned)ra;
}

__global__ void k_initcur(int NB, int* gcur) {
    int i = blockIdx.x * blockDim.x + threadIdx.x;
    if (i < NB) gcur[i] = i * CAPB;
}

// Phase 1: bucket edges by dst>>7 into fixed regions; packed u32 = (dst<<16)|src.
__global__ void k_bucket(int E, const int* __restrict__ src, const int* __restrict__ dst,
                         int* gcur, unsigned* __restrict__ bucketed, int NB) {
    __shared__ int lh[512];
    __shared__ int lbase[512];
    int t = threadIdx.x;
    int e0 = blockIdx.x * 8192;
    for (int i = t; i < NB; i += 256) lh[i] = 0;
    __syncthreads();
    for (int k = 0; k < 32; ++k) {
        int e = e0 + k * 256 + t;
        if (e < E) atomicAdd(&lh[((unsigned)dst[e]) >> 7], 1);
    }
    __syncthreads();
    for (int i = t; i < NB; i += 256) {
        int c = lh[i];
        lbase[i] = (c > 0) ? atomicAdd(&gcur[i], c) : 0;
        lh[i] = 0;
    }
    __syncthreads();
    for (int k = 0; k < 32; ++k) {
        int e = e0 + k * 256 + t;
        if (e < E) {
            int d = dst[e], s = src[e];
            int b = ((unsigned)d) >> 7;
            int r = atomicAdd(&lh[b], 1);
            int pos = lbase[b] + r;
            if (pos < (b + 1) * CAPB)
                bucketed[pos] = ((unsigned)d << 16) | (unsigned)s;
        }
    }
}

// Exclusive scan of bucket counts -> gstart; rowptr[N].
__global__ void k_bktscan(int NB, int N, const int* __restrict__ gcur,
                          int* gstart, int* rowptr) {
    __shared__ int sd[512];
    int t = threadIdx.x;
    int c = (t < NB) ? min(gcur[t] - t * CAPB, CAPB) : 0;
    sd[t] = c;
    __syncthreads();
    int x = c;
    for (int s = 1; s < 512; s <<= 1) {
        int p = (t >= s) ? sd[t - s] : 0;
        __syncthreads();
        x += p;
        sd[t] = x;
        __syncthreads();
    }
    if (t < NB) gstart[t] = x - c;
    if (t == NB - 1) {
        gstart[NB] = x;
        rowptr[N] = x;
    }
}

// Phase 2: per bucket, LDS hist+scan over 128 local dsts -> rowptr/ssinv + coalesced csr.
__global__ void k_csr(int N, const unsigned* __restrict__ bucketed, const int* __restrict__ gcur,
                      const int* __restrict__ gstart, unsigned short* __restrict__ csr,
                      int* __restrict__ rowptr, float* __restrict__ ssinv) {
    __shared__ unsigned st[BCAP];
    __shared__ int hist[128], cur[128], sgp[128];
    int b = blockIdx.x, t = threadIdx.x;
    int n0 = b << 7;
    int nn = min(128, N - n0);
    int cnt = min(gcur[b] - b * CAPB, CAPB);
    int base = gstart[b];
    if (t < 128) { hist[t] = 0; sgp[t] = 0; }
    __syncthreads();
    bool single = (cnt <= BCAP);
    for (int off = 0; off < cnt; off += BCAP) {
        int bs = min(BCAP, cnt - off);
        for (int i = t; i < bs; i += 256) {
            unsigned w = bucketed[b * CAPB + off + i];
            if (single) st[i] = w;
            int d = (int)(w >> 16);
            int s = (int)(w & 0xffffu);
            int dl = d - n0;
            atomicAdd(&hist[dl], 1);
            atomicAdd(&sgp[dl], ((s < d) ? 1024 : 0) + ((s == d) ? 1 : 0));
        }
    }
    __syncthreads();
    int deg_t = (t < 128) ? hist[t] : 0;
    int x = deg_t;
    for (int s = 1; s < 128; s <<= 1) {
        int p = (t < 128 && t >= s) ? hist[t - s] : 0;
        __syncthreads();
        if (t < 128) { x += p; hist[t] = x; }
        __syncthreads();
    }
    if (t < 128) {
        int excl = hist[t] - deg_t;
        cur[t] = excl;
        if (t < nn) {
            rowptr[n0 + t] = base + excl;
            int sg = sgp[t];
            int lt = sg >> 10, eq = sg & 1023;
            float ss = (float)(deg_t - eq - 2 * lt);
            ssinv[n0 + t] = (deg_t > 0) ? ss / (float)deg_t : 0.f;
        }
    }
    __syncthreads();
    for (int off = 0; off < cnt; off += BCAP) {
        int bs = min(BCAP, cnt - off);
        if (!single) {
            for (int i = t; i < bs; i += 256) st[i] = bucketed[b * CAPB + off + i];
            __syncthreads();
        }
        for (int i = t; i < bs; i += 256) {
            unsigned w = st[i];
            int dl = (int)(w >> 16) - n0;
            int p = atomicAdd(&cur[dl], 1);
            csr[base + p] = (unsigned short)(w & 0xffffu);
        }
        if (!single) __syncthreads();
    }
}

// WT[l][h][k]: h<64 -> A[k][h]=W[k][h]-W[64+k][h]; h>=64 -> W2[k][h-64]=W[64+k][h-64]
__global__ void k_prep(int total, const float* __restrict__ W_mid, float* __restrict__ WT) {
    int i = blockIdx.x * blockDim.x + threadIdx.x;
    if (i >= total) return;
    int l = i >> 13;
    int rem = i & 8191;
    int h = rem >> 6;
    int k = rem & 63;
    const float* W = W_mid + (size_t)l * 129 * 64;
    float v;
    if (h < 64) v = W[k * 64 + h] - W[(64 + k) * 64 + h];
    else        v = W[(64 + k) * 64 + (h - 64)];
    WT[i] = v;
}

// conv_in: x [N,1] fp32 -> packed fp16 [N,32] dwords
__global__ void k_in(int N, const float* __restrict__ x0,
                     const int* __restrict__ rowptr, const unsigned short* __restrict__ csr,
                     const float* __restrict__ ssinv,
                     const float* __restrict__ W_in, const float* __restrict__ b_in,
                     unsigned* __restrict__ xoutP) {
    int wid = blockIdx.x * (blockDim.x >> 6) + (threadIdx.x >> 6);
    int lane = threadIdx.x & 63;
    if (wid >= N) return;
    int beg = rowptr[wid], end = rowptr[wid + 1];
    int deg = end - beg;
    float s = 0.f;
    for (int e = beg + lane; e < end; e += 64) s += x0[csr[e]];
    for (int m = 32; m >= 1; m >>= 1) s += __shfl_xor(s, m, 64);
    float invd = 1.f / (float)max(deg, 1);
    float mean = s * invd;
    float xi = x0[wid];
    float w1 = W_in[lane], w2 = W_in[64 + lane], w3 = W_in[128 + lane];
    float y = xi * (w1 - w2) + mean * w2 + ssinv[wid] * w3 + b_in[lane];
    if (deg == 0) y = 0.f;
    float ylo = __shfl(y, (2 * lane) & 63, 64);
    float yhi = __shfl(y, (2 * lane + 1) & 63, 64);
    unsigned pkd = packh(ylo, yhi);
    if (lane < 32) xoutP[(size_t)wid * 32 + lane] = pkd;
}

// one h-pair of the GEMM: y[h] and y[h+1] for this lane's node
static __device__ __forceinline__ unsigned hpair(const float* xf, const float* wbase, int h) {
    const float4* wa = (const float4*)(wbase + h * 64);
    const float4* wb = (const float4*)(wbase + (h + 1) * 64);
    float a0 = 0.f, a1 = 0.f, a2 = 0.f, a3 = 0.f;
    float b0 = 0.f, b1 = 0.f, b2 = 0.f, b3 = 0.f;
#pragma unroll
    for (int j = 0; j < 16; ++j) {
        float4 A = wa[j], B = wb[j];
        a0 = fmaf(xf[4 * j + 0], A.x, a0);
        a1 = fmaf(xf[4 * j + 1], A.y, a1);
        a2 = fmaf(xf[4 * j + 2], A.z, a2);
        a3 = fmaf(xf[4 * j + 3], A.w, a3);
        b0 = fmaf(xf[4 * j + 0], B.x, b0);
        b1 = fmaf(xf[4 * j + 1], B.y, b1);
        b2 = fmaf(xf[4 * j + 2], B.z, b2);
        b3 = fmaf(xf[4 * j + 3], B.w, b3);
    }
    return packh((a0 + a1) + (a2 + a3), (b0 + b1) + (b2 + b3));
}

// dense Y = X @ [A | W2]; lane = node, wave = 64 nodes x 32 h-outputs (hq quarter)
__global__ __launch_bounds__(256) void k_gemm(
        int N, const unsigned* __restrict__ xP, const float* __restrict__ WTl,
        unsigned* __restrict__ Y1P, unsigned* __restrict__ Y2P) {
    int gw = blockIdx.x * 4 + (threadIdx.x >> 6);
    int ng = gw >> 2;
    int hq = __builtin_amdgcn_readfirstlane(gw & 3);
    int lane = threadIdx.x & 63;
    int node = ng * 64 + lane;
    bool valid = (node < N);

    float xf[64];
    const uint4* xr = (const uint4*)(xP + (size_t)node * 32);
#pragma unroll
    for (int j = 0; j < 8; ++j) {
        uint4 d = valid ? xr[j] : make_uint4(0u, 0u, 0u, 0u);
        xf[8 * j + 0] = h_lo(d.x); xf[8 * j + 1] = h_hi(d.x);
        xf[8 * j + 2] = h_lo(d.y); xf[8 * j + 3] = h_hi(d.y);
        xf[8 * j + 4] = h_lo(d.z); xf[8 * j + 5] = h_hi(d.z);
        xf[8 * j + 6] = h_lo(d.w); xf[8 * j + 7] = h_hi(d.w);
    }
    unsigned* Yp = (hq < 2) ? Y1P : Y2P;
    int dbase = (hq & 1) ? 16 : 0;
    const float* w0 = WTl + hq * 32 * 64;

    for (int c = 0; c < 4; ++c) {
        unsigned p0 = hpair(xf, w0, c * 8 + 0);
        unsigned p1 = hpair(xf, w0, c * 8 + 2);
        unsigned p2 = hpair(xf, w0, c * 8 + 4);
        unsigned p3 = hpair(xf, w0, c * 8 + 6);
        if (valid)
            *((uint4*)(Yp + (size_t)node * 32 + dbase + c * 4)) = make_uint4(p0, p1, p2, p3);
    }
}

// lean aggregation: x' = leaky(Y1 + mean_gather(Y2) + ss*W3 + bias (+res))
template <bool RES, bool TOUT>
__global__ __launch_bounds__(256) void k_agg(
        int N, const unsigned* __restrict__ Y1P, const unsigned* __restrict__ Y2P,
        const unsigned* __restrict__ xresP, unsigned* __restrict__ xoutP,
        const int* __restrict__ rowptr, const unsigned short* __restrict__ csr,
        const float* __restrict__ ssinv,
        const float* __restrict__ W3, const float* __restrict__ bias,
        const float* __restrict__ Wt, float* __restrict__ t) {
    int wid = blockIdx.x * 4 + (threadIdx.x >> 6);
    int lane = threadIdx.x & 63;
    if (wid >= N) return;
    int beg = __builtin_amdgcn_readfirstlane(rowptr[wid]);
    int end = __builtin_amdgcn_readfirstlane(rowptr[wid + 1]);
    int deg = end - beg;
    int w = lane & 31;
    int half = lane >> 5;
    float acc0 = 0.f, acc1 = 0.f;
    for (int tbase = beg; tbase < end; tbase += 64) {
        int cnt = min(64, end - tbase);
        int sv = (lane < cnt) ? (int)csr[tbase + lane] : -1;
        for (int u = 0; u < cnt; u += 8) {
            int i0 = __builtin_amdgcn_readlane(sv, u);
            int i1 = __builtin_amdgcn_readlane(sv, u + 1);
            int i2 = __builtin_amdgcn_readlane(sv, u + 2);
            int i3 = __builtin_amdgcn_readlane(sv, u + 3);
            int i4 = __builtin_amdgcn_readlane(sv, u + 4);
            int i5 = __builtin_amdgcn_readlane(sv, u + 5);
            int i6 = __builtin_amdgcn_readlane(sv, u + 6);
            int i7 = __builtin_amdgcn_readlane(sv, u + 7);
            int a0 = half ? i1 : i0;
            int a1 = half ? i3 : i2;
            int a2 = half ? i5 : i4;
            int a3 = half ? i7 : i6;
            if (a0 >= 0) { unsigned d = Y2P[(size_t)a0 * 32 + w]; acc0 += h_lo(d); acc1 += h_hi(d); }
            if (a1 >= 0) { unsigned d = Y2P[(size_t)a1 * 32 + w]; acc0 += h_lo(d); acc1 += h_hi(d); }
            if (a2 >= 0) { unsigned d = Y2P[(size_t)a2 * 32 + w]; acc0 += h_lo(d); acc1 += h_hi(d); }
            if (a3 >= 0) { unsigned d = Y2P[(size_t)a3 * 32 + w]; acc0 += h_lo(d); acc1 += h_hi(d); }
        }
    }
    acc0 += __shfl_xor(acc0, 32, 64);
    acc1 += __shfl_xor(acc1, 32, 64);
    float invd = 1.f / (float)max(deg, 1);
    unsigned y1d = Y1P[(size_t)wid * 32 + w];
    float ss = ssinv[wid];
    float2 w3 = ((const float2*)W3)[w];
    float2 bb = ((const float2*)bias)[w];
    float y0 = h_lo(y1d) + acc0 * invd + ss * w3.x + bb.x;
    float y1 = h_hi(y1d) + acc1 * invd + ss * w3.y + bb.y;
    if (deg == 0) { y0 = 0.f; y1 = 0.f; }
    if (RES) {
        unsigned r = xresP[(size_t)wid * 32 + w];
        y0 += h_lo(r);
        y1 += h_hi(r);
    }
    y0 = (y0 > 0.f) ? y0 : NEG_SLOPE * y0;
    y1 = (y1 > 0.f) ? y1 : NEG_SLOPE * y1;
    if (TOUT) {
        float2 wt = ((const float2*)Wt)[w];
        float tp = y0 * wt.x + y1 * wt.y;
        for (int m = 16; m >= 1; m >>= 1) tp += __shfl_xor(tp, m, 64);
        if (lane == 0) t[wid] = tp;
    }
    if (lane < 32) xoutP[(size_t)wid * 32 + w] = packh(y0, y1);
}

// conv_out + residual x
__global__ void k_out(int N, const unsigned* __restrict__ xAP, const float* __restrict__ x0,
                      const int* __restrict__ rowptr, const unsigned short* __restrict__ csr,
                      const float* __restrict__ ssinv, const float* __restrict__ t,
                      const float* __restrict__ W_out, const float* __restrict__ b_out,
                      float* __restrict__ out) {
    int wid = blockIdx.x * (blockDim.x >> 6) + (threadIdx.x >> 6);
    int lane = threadIdx.x & 63;
    if (wid >= N) return;
    int beg = rowptr[wid], end = rowptr[wid + 1];
    int deg = end - beg;
    float s = 0.f;
    for (int e = beg + lane; e < end; e += 64) s += t[csr[e]];
    unsigned xw = xAP[(size_t)wid * 32 + (lane >> 1)];
    float xf = (lane & 1) ? h_hi(xw) : h_lo(xw);
    float p = xf * (W_out[lane] - W_out[64 + lane]);
    for (int m = 32; m >= 1; m >>= 1) {
        s += __shfl_xor(s, m, 64);
        p += __shfl_xor(p, m, 64);
    }
    float invd = 1.f / (float)max(deg, 1);
    float y = p + s * invd + ssinv[wid] * W_out[128] + b_out[0];
    if (deg == 0) y = 0.f;
    if (lane == 0) out[wid] = y + x0[wid];
}

static inline size_t align16(size_t x) { return (x + 15) & ~(size_t)15; }

extern "C" void kernel_launch(void* const* d_in, const int* in_sizes, int n_in,
                              void* d_out, int out_size, void* d_ws, size_t ws_size,
                              hipStream_t stream) {
    const float* x0    = (const float*)d_in[0];
    const int*   ei    = (const int*)d_in[1];
    const float* W_in  = (const float*)d_in[2];
    const float* b_in  = (const float*)d_in[3];
    const float* W_mid = (const float*)d_in[4];
    const float* b_mid = (const float*)d_in[5];
    const float* W_out = (const float*)d_in[6];
    const float* b_out = (const float*)d_in[7];
    float* out = (float*)d_out;

    const int N = in_sizes[0];
    const int E = in_sizes[1] / 2;
    const int L = in_sizes[4] / (129 * 64);
    const int NB = (N + 127) >> 7;
    const int* src = ei;
    const int* dst = ei + E;

    char* p = (char*)d_ws;
    float* WT     = (float*)p; p += align16((size_t)L * 128 * 64 * 4);
    unsigned* xAP = (unsigned*)p; p += align16((size_t)N * 32 * 4);
    unsigned* xBP = (unsigned*)p; p += align16((size_t)N * 32 * 4);
    // bucketed aliases Y1P/Y2P: bucketed dead before first k_gemm
    size_t rsz = (size_t)NB * CAPB * 4;
    size_t ysz = (size_t)N * 32 * 4 * 2;
    unsigned* bucketed = (unsigned*)p;
    unsigned* Y1P = (unsigned*)p;
    unsigned* Y2P = (unsigned*)(p + (size_t)N * 32 * 4);
    p += align16(rsz > ysz ? rsz : ysz);
    unsigned short* csr = (unsigned short*)p; p += align16((size_t)E * 2);
    int* gcur          = (int*)p; p += align16((size_t)(NB + 1) * 4);
    int* gstart        = (int*)p; p += align16((size_t)(NB + 1) * 4);
    int* rowptr        = (int*)p; p += align16((size_t)(N + 1) * 4);
    float* ssinv       = (float*)p; p += align16((size_t)N * 4);
    float* t           = (float*)p; p += align16((size_t)N * 4);

    const int nb_w4 = (N + 3) / 4;
    const int nb_bkt = (E + 8191) / 8192;
    const int ptotal = L * 128 * 64;
    const int nb_gemm = (N + 63) / 64;

    k_initcur<<<(NB + 255) / 256, 256, 0, stream>>>(NB, gcur);
    k_bucket<<<nb_bkt, 256, 0, stream>>>(E, src, dst, gcur, bucketed, NB);
    k_bktscan<<<1, 512, 0, stream>>>(NB, N, gcur, gstart, rowptr);
    k_csr<<<NB, 256, 0, stream>>>(N, bucketed, gcur, gstart, csr, rowptr, ssinv);
    k_prep<<<(ptotal + 255) / 256, 256, 0, stream>>>(ptotal, W_mid, WT);

    k_in<<<nb_w4, 256, 0, stream>>>(N, x0, rowptr, csr, ssinv, W_in, b_in, xAP);

    for (int l = 0; l < L / 2; ++l) {
        bool last = (l == L / 2 - 1);
        const float* WTa = WT + (size_t)(2 * l) * 128 * 64;
        const float* WTb = WT + (size_t)(2 * l + 1) * 128 * 64;
        const float* W3a = W_mid + (size_t)(2 * l) * 129 * 64 + 128 * 64;
        const float* W3b = W_mid + (size_t)(2 * l + 1) * 129 * 64 + 128 * 64;

        // x1 = leaky(conv(x2)) : xAP -> xBP
        k_gemm<<<nb_gemm, 256, 0, stream>>>(N, xAP, WTa, Y1P, Y2P);
        k_agg<false, false><<<nb_w4, 256, 0, stream>>>(
            N, Y1P, Y2P, nullptr, xBP, rowptr, csr, ssinv,
            W3a, b_mid + (size_t)(2 * l) * HDIM, nullptr, nullptr);

        // x2 = leaky(conv(x1) + x2) : xBP (+xAP) -> xAP  [+ t on last]
        k_gemm<<<nb_gemm, 256, 0, stream>>>(N, xBP, WTb, Y1P, Y2P);
        if (!last) {
            k_agg<true, false><<<nb_w4, 256, 0, stream>>>(
                N, Y1P, Y2P, xAP, xAP, rowptr, csr, ssinv,
                W3b, b_mid + (size_t)(2 * l + 1) * HDIM, nullptr, nullptr);
        } else {
            k_agg<true, true><<<nb_w4, 256, 0, stream>>>(
                N, Y1P, Y2P, xAP, xAP, rowptr, csr, ssinv,
                W3b, b_mid + (size_t)(2 * l + 1) * HDIM, W_out + 64, t);
        }
    }

    k_out<<<nb_w4, 256, 0, stream>>>(N, xAP, x0, rowptr, csr, ssinv, t,
                                     W_out, b_out, out);
}

// Round 5
// 497.977 us; speedup vs baseline: 1.2752x; 1.2752x over previous
//
#include <hip/hip_runtime.h>
#include <hip/hip_fp16.h>

#define HDIM 64
#define NEG_SLOPE 0.01f
#define CAPB 8192      // bucketed[] region per 128-node bucket
#define BCAP 6144      // LDS staging capacity in k_csr

typedef _Float16 half8 __attribute__((ext_vector_type(8)));
typedef float f32x4 __attribute__((ext_vector_type(4)));

static __device__ __forceinline__ float h_lo(unsigned d) {
    return __half2float(__ushort_as_half((unsigned short)(d & 0xffffu)));
}
static __device__ __forceinline__ float h_hi(unsigned d) {
    return __half2float(__ushort_as_half((unsigned short)(d >> 16)));
}
static __device__ __forceinline__ unsigned packh(float a, float b) {
    unsigned short ra = __half_as_ushort(__float2half(a));
    unsigned short rb = __half_as_ushort(__float2half(b));
    return ((unsigned)rb << 16) | (unsigned)ra;
}
static __device__ __forceinline__ half8 u4h(uint4 v) {
    union { uint4 u; half8 h; } x; x.u = v; return x.h;
}

__global__ void k_initcur(int NB, int* gcur) {
    int i = blockIdx.x * blockDim.x + threadIdx.x;
    if (i < NB) gcur[i] = i * CAPB;
}

// Phase 1: bucket edges by dst>>7 into fixed regions; packed u32 = (dst<<16)|src.
__global__ void k_bucket(int E, const int* __restrict__ src, const int* __restrict__ dst,
                         int* gcur, unsigned* __restrict__ bucketed, int NB) {
    __shared__ int lh[512];
    __shared__ int lbase[512];
    int t = threadIdx.x;
    int e0 = blockIdx.x * 8192;
    for (int i = t; i < NB; i += 256) lh[i] = 0;
    __syncthreads();
    for (int k = 0; k < 32; ++k) {
        int e = e0 + k * 256 + t;
        if (e < E) atomicAdd(&lh[((unsigned)dst[e]) >> 7], 1);
    }
    __syncthreads();
    for (int i = t; i < NB; i += 256) {
        int c = lh[i];
        lbase[i] = (c > 0) ? atomicAdd(&gcur[i], c) : 0;
        lh[i] = 0;
    }
    __syncthreads();
    for (int k = 0; k < 32; ++k) {
        int e = e0 + k * 256 + t;
        if (e < E) {
            int d = dst[e], s = src[e];
            int b = ((unsigned)d) >> 7;
            int r = atomicAdd(&lh[b], 1);
            int pos = lbase[b] + r;
            if (pos < (b + 1) * CAPB)
                bucketed[pos] = ((unsigned)d << 16) | (unsigned)s;
        }
    }
}

// Exclusive scan of bucket counts -> gstart; rowptr[N].
__global__ void k_bktscan(int NB, int N, const int* __restrict__ gcur,
                          int* gstart, int* rowptr) {
    __shared__ int sd[512];
    int t = threadIdx.x;
    int c = (t < NB) ? min(gcur[t] - t * CAPB, CAPB) : 0;
    sd[t] = c;
    __syncthreads();
    int x = c;
    for (int s = 1; s < 512; s <<= 1) {
        int p = (t >= s) ? sd[t - s] : 0;
        __syncthreads();
        x += p;
        sd[t] = x;
        __syncthreads();
    }
    if (t < NB) gstart[t] = x - c;
    if (t == NB - 1) {
        gstart[NB] = x;
        rowptr[N] = x;
    }
}

// Phase 2: per bucket, LDS hist+scan over 128 local dsts -> rowptr/ssinv + coalesced csr.
__global__ void k_csr(int N, const unsigned* __restrict__ bucketed, const int* __restrict__ gcur,
                      const int* __restrict__ gstart, unsigned short* __restrict__ csr,
                      int* __restrict__ rowptr, float* __restrict__ ssinv) {
    __shared__ unsigned st[BCAP];
    __shared__ int hist[128], cur[128], sgp[128];
    int b = blockIdx.x, t = threadIdx.x;
    int n0 = b << 7;
    int nn = min(128, N - n0);
    int cnt = min(gcur[b] - b * CAPB, CAPB);
    int base = gstart[b];
    if (t < 128) { hist[t] = 0; sgp[t] = 0; }
    __syncthreads();
    bool single = (cnt <= BCAP);
    for (int off = 0; off < cnt; off += BCAP) {
        int bs = min(BCAP, cnt - off);
        for (int i = t; i < bs; i += 256) {
            unsigned w = bucketed[b * CAPB + off + i];
            if (single) st[i] = w;
            int d = (int)(w >> 16);
            int s = (int)(w & 0xffffu);
            int dl = d - n0;
            atomicAdd(&hist[dl], 1);
            atomicAdd(&sgp[dl], ((s < d) ? 1024 : 0) + ((s == d) ? 1 : 0));
        }
    }
    __syncthreads();
    int deg_t = (t < 128) ? hist[t] : 0;
    int x = deg_t;
    for (int s = 1; s < 128; s <<= 1) {
        int p = (t < 128 && t >= s) ? hist[t - s] : 0;
        __syncthreads();
        if (t < 128) { x += p; hist[t] = x; }
        __syncthreads();
    }
    if (t < 128) {
        int excl = hist[t] - deg_t;
        cur[t] = excl;
        if (t < nn) {
            rowptr[n0 + t] = base + excl;
            int sg = sgp[t];
            int lt = sg >> 10, eq = sg & 1023;
            float ss = (float)(deg_t - eq - 2 * lt);
            ssinv[n0 + t] = (deg_t > 0) ? ss / (float)deg_t : 0.f;
        }
    }
    __syncthreads();
    for (int off = 0; off < cnt; off += BCAP) {
        int bs = min(BCAP, cnt - off);
        if (!single) {
            for (int i = t; i < bs; i += 256) st[i] = bucketed[b * CAPB + off + i];
            __syncthreads();
        }
        for (int i = t; i < bs; i += 256) {
            unsigned w = st[i];
            int dl = (int)(w >> 16) - n0;
            int p = atomicAdd(&cur[dl], 1);
            csr[base + p] = (unsigned short)(w & 0xffffu);
        }
        if (!single) __syncthreads();
    }
}

// WTh[l][h][k] fp16: B[k][h] = W[k][h] - (k<64 ? W[64+k][h] : 0)   (k<64: A, k>=64: W2)
__global__ void k_prep(int total, const float* __restrict__ W_mid,
                       unsigned short* __restrict__ WTh) {
    int i = blockIdx.x * blockDim.x + threadIdx.x;
    if (i >= total) return;
    int l = i >> 13;
    int rem = i & 8191;
    int h = rem >> 7;
    int k = rem & 127;
    const float* W = W_mid + (size_t)l * 129 * 64;
    float v = W[k * 64 + h] - ((k < 64) ? W[(64 + k) * 64 + h] : 0.f);
    WTh[i] = __half_as_ushort(__float2half(v));
}

// conv_in: x [N,1] fp32 -> packed fp16 [N,32] dwords
__global__ void k_in(int N, const float* __restrict__ x0,
                     const int* __restrict__ rowptr, const unsigned short* __restrict__ csr,
                     const float* __restrict__ ssinv,
                     const float* __restrict__ W_in, const float* __restrict__ b_in,
                     unsigned* __restrict__ xoutP) {
    int wid = blockIdx.x * (blockDim.x >> 6) + (threadIdx.x >> 6);
    int lane = threadIdx.x & 63;
    if (wid >= N) return;
    int beg = rowptr[wid], end = rowptr[wid + 1];
    int deg = end - beg;
    float s = 0.f;
    for (int e = beg + lane; e < end; e += 64) s += x0[csr[e]];
    for (int m = 32; m >= 1; m >>= 1) s += __shfl_xor(s, m, 64);
    float invd = 1.f / (float)max(deg, 1);
    float mean = s * invd;
    float xi = x0[wid];
    float w1 = W_in[lane], w2 = W_in[64 + lane], w3 = W_in[128 + lane];
    float y = xi * (w1 - w2) + mean * w2 + ssinv[wid] * w3 + b_in[lane];
    if (deg == 0) y = 0.f;
    float ylo = __shfl(y, (2 * lane) & 63, 64);
    float yhi = __shfl(y, (2 * lane + 1) & 63, 64);
    unsigned pkd = packh(ylo, yhi);
    if (lane < 32) xoutP[(size_t)wid * 32 + lane] = pkd;
}

// Fused layer: gather mean(x_j) -> LDS A=[x_i|M] fp16 -> MFMA with [A;W2] -> epilogue.
// Block = 256 threads = 16 nodes; wave w owns output h-tile [16w,16w+16).
template <bool RES>
__global__ __launch_bounds__(256) void k_layer(
        int N, const unsigned* __restrict__ xinP,
        const unsigned* __restrict__ xresP, unsigned* __restrict__ xoutP,
        const int* __restrict__ rowptr, const unsigned short* __restrict__ csr,
        const float* __restrict__ ssinv,
        const unsigned short* __restrict__ WThl,   // [64 h][128 k] fp16
        const float* __restrict__ W3, const float* __restrict__ bias) {
    __shared__ unsigned Ald[16 * 64];   // 16 nodes x 64 dwords (128 f16), XOR-swizzled
    __shared__ float Cld[16 * 64];
    __shared__ int sdeg[16];
    __shared__ float sss[16];

    int t = threadIdx.x;
    int lane = t & 63;
    int wv = t >> 6;
    int n0 = blockIdx.x << 4;
    int kg = lane >> 4;

    // B-fragments for this wave's h-tile (live in 16 VGPRs the whole kernel)
    int cb = (wv << 4) + (lane & 15);
    const uint4* wp = (const uint4*)WThl;
    uint4 b0 = wp[cb * 16 + kg + 0];
    uint4 b1 = wp[cb * 16 + kg + 4];
    uint4 b2 = wp[cb * 16 + kg + 8];
    uint4 b3 = wp[cb * 16 + kg + 12];

    int w = lane & 31;
    int half = lane >> 5;

    // ---- gather phase: wave handles 4 nodes sequentially ----
    for (int q = 0; q < 4; ++q) {
        int nd = (wv << 2) + q;
        int node = n0 + nd;
        float acc0 = 0.f, acc1 = 0.f;
        int deg = 0;
        unsigned xiw = 0u;
        float ssv = 0.f;
        if (node < N) {
            int beg = __builtin_amdgcn_readfirstlane(rowptr[node]);
            int end = __builtin_amdgcn_readfirstlane(rowptr[node + 1]);
            deg = end - beg;
            for (int tbase = beg; tbase < end; tbase += 64) {
                int cnt = min(64, end - tbase);
                int sv = (lane < cnt) ? (int)csr[tbase + lane] : -1;
                for (int u = 0; u < cnt; u += 8) {
                    int i0 = __builtin_amdgcn_readlane(sv, u);
                    int i1 = __builtin_amdgcn_readlane(sv, u + 1);
                    int i2 = __builtin_amdgcn_readlane(sv, u + 2);
                    int i3 = __builtin_amdgcn_readlane(sv, u + 3);
                    int i4 = __builtin_amdgcn_readlane(sv, u + 4);
                    int i5 = __builtin_amdgcn_readlane(sv, u + 5);
                    int i6 = __builtin_amdgcn_readlane(sv, u + 6);
                    int i7 = __builtin_amdgcn_readlane(sv, u + 7);
                    int a0 = half ? i1 : i0;
                    int a1 = half ? i3 : i2;
                    int a2 = half ? i5 : i4;
                    int a3 = half ? i7 : i6;
                    if (a0 >= 0) { unsigned d = xinP[(size_t)a0 * 32 + w]; acc0 += h_lo(d); acc1 += h_hi(d); }
                    if (a1 >= 0) { unsigned d = xinP[(size_t)a1 * 32 + w]; acc0 += h_lo(d); acc1 += h_hi(d); }
                    if (a2 >= 0) { unsigned d = xinP[(size_t)a2 * 32 + w]; acc0 += h_lo(d); acc1 += h_hi(d); }
                    if (a3 >= 0) { unsigned d = xinP[(size_t)a3 * 32 + w]; acc0 += h_lo(d); acc1 += h_hi(d); }
                }
            }
            if (lane < 32) xiw = xinP[(size_t)node * 32 + w];
            ssv = ssinv[node];
        }
        acc0 += __shfl_xor(acc0, 32, 64);
        acc1 += __shfl_xor(acc1, 32, 64);
        float invd = 1.f / (float)max(deg, 1);
        unsigned mw = packh(acc0 * invd, acc1 * invd);
        if (lane < 32) {
            int gx = (w >> 2) ^ (nd & 7);                // x_i: dword cols 0..31 (k 0..63)
            Ald[nd * 64 + gx * 4 + (w & 3)] = xiw;
            int gm = (((32 + w) >> 2)) ^ (nd & 7);       // M: dword cols 32..63 (k 64..127)
            Ald[nd * 64 + gm * 4 + (w & 3)] = mw;
        }
        if (lane == 0) { sdeg[nd] = deg; sss[nd] = ssv; }
    }
    __syncthreads();

    // ---- MFMA: C[16 nodes][16 h] = A[16][128] @ B[128][16] ----
    int r = lane & 15;
    const uint4* ap = (const uint4*)Ald;
    int rx = (r & 7);
    uint4 a0 = ap[r * 16 + ((0 + kg) ^ rx)];
    uint4 a1 = ap[r * 16 + ((4 + kg) ^ rx)];
    uint4 a2 = ap[r * 16 + ((8 + kg) ^ rx)];
    uint4 a3 = ap[r * 16 + ((12 + kg) ^ rx)];
    f32x4 acc = {0.f, 0.f, 0.f, 0.f};
    acc = __builtin_amdgcn_mfma_f32_16x16x32_f16(u4h(a0), u4h(b0), acc, 0, 0, 0);
    acc = __builtin_amdgcn_mfma_f32_16x16x32_f16(u4h(a1), u4h(b1), acc, 0, 0, 0);
    acc = __builtin_amdgcn_mfma_f32_16x16x32_f16(u4h(a2), u4h(b2), acc, 0, 0, 0);
    acc = __builtin_amdgcn_mfma_f32_16x16x32_f16(u4h(a3), u4h(b3), acc, 0, 0, 0);
#pragma unroll
    for (int reg = 0; reg < 4; ++reg)
        Cld[(kg * 4 + reg) * 64 + (wv << 4) + r] = acc[reg];
    __syncthreads();

    // ---- epilogue: thread t -> node t>>4, dword cols (t&15) and (t&15)+16 ----
    int nd = t >> 4;
    int node = n0 + nd;
    if (node < N) {
        int dg = sdeg[nd];
        float ss = sss[nd];
#pragma unroll
        for (int jj = 0; jj < 2; ++jj) {
            int j = (t & 15) + jj * 16;
            float y0 = Cld[nd * 64 + 2 * j];
            float y1 = Cld[nd * 64 + 2 * j + 1];
            float2 w3 = ((const float2*)W3)[j];
            float2 bb = ((const float2*)bias)[j];
            y0 += ss * w3.x + bb.x;
            y1 += ss * w3.y + bb.y;
            if (dg == 0) { y0 = 0.f; y1 = 0.f; }
            if (RES) {
                unsigned rw = xresP[(size_t)node * 32 + j];
                y0 += h_lo(rw);
                y1 += h_hi(rw);
            }
            y0 = (y0 > 0.f) ? y0 : NEG_SLOPE * y0;
            y1 = (y1 > 0.f) ? y1 : NEG_SLOPE * y1;
            xoutP[(size_t)node * 32 + j] = packh(y0, y1);
        }
    }
}

// t[i] = dot(x'[i], W_out[64:128])
__global__ void k_t(int N, const unsigned* __restrict__ xAP, const float* __restrict__ Wt,
                    float* __restrict__ t) {
    int wid = blockIdx.x * (blockDim.x >> 6) + (threadIdx.x >> 6);
    int lane = threadIdx.x & 63;
    if (wid >= N) return;
    float p = 0.f;
    if (lane < 32) {
        unsigned d = xAP[(size_t)wid * 32 + lane];
        float2 wt = ((const float2*)Wt)[lane];
        p = h_lo(d) * wt.x + h_hi(d) * wt.y;
    }
    for (int m = 32; m >= 1; m >>= 1) p += __shfl_xor(p, m, 64);
    if (lane == 0) t[wid] = p;
}

// conv_out + residual x
__global__ void k_out(int N, const unsigned* __restrict__ xAP, const float* __restrict__ x0,
                      const int* __restrict__ rowptr, const unsigned short* __restrict__ csr,
                      const float* __restrict__ ssinv, const float* __restrict__ t,
                      const float* __restrict__ W_out, const float* __restrict__ b_out,
                      float* __restrict__ out) {
    int wid = blockIdx.x * (blockDim.x >> 6) + (threadIdx.x >> 6);
    int lane = threadIdx.x & 63;
    if (wid >= N) return;
    int beg = rowptr[wid], end = rowptr[wid + 1];
    int deg = end - beg;
    float s = 0.f;
    for (int e = beg + lane; e < end; e += 64) s += t[csr[e]];
    unsigned xw = xAP[(size_t)wid * 32 + (lane >> 1)];
    float xf = (lane & 1) ? h_hi(xw) : h_lo(xw);
    float p = xf * (W_out[lane] - W_out[64 + lane]);
    for (int m = 32; m >= 1; m >>= 1) {
        s += __shfl_xor(s, m, 64);
        p += __shfl_xor(p, m, 64);
    }
    float invd = 1.f / (float)max(deg, 1);
    float y = p + s * invd + ssinv[wid] * W_out[128] + b_out[0];
    if (deg == 0) y = 0.f;
    if (lane == 0) out[wid] = y + x0[wid];
}

static inline size_t align16(size_t x) { return (x + 15) & ~(size_t)15; }

extern "C" void kernel_launch(void* const* d_in, const int* in_sizes, int n_in,
                              void* d_out, int out_size, void* d_ws, size_t ws_size,
                              hipStream_t stream) {
    const float* x0    = (const float*)d_in[0];
    const int*   ei    = (const int*)d_in[1];
    const float* W_in  = (const float*)d_in[2];
    const float* b_in  = (const float*)d_in[3];
    const float* W_mid = (const float*)d_in[4];
    const float* b_mid = (const float*)d_in[5];
    const float* W_out = (const float*)d_in[6];
    const float* b_out = (const float*)d_in[7];
    float* out = (float*)d_out;

    const int N = in_sizes[0];
    const int E = in_sizes[1] / 2;
    const int L = in_sizes[4] / (129 * 64);
    const int NB = (N + 127) >> 7;
    const int* src = ei;
    const int* dst = ei + E;

    char* p = (char*)d_ws;
    unsigned short* WTh = (unsigned short*)p; p += align16((size_t)L * 64 * 128 * 2);
    unsigned* xAP = (unsigned*)p; p += align16((size_t)N * 32 * 4);
    unsigned* xBP = (unsigned*)p; p += align16((size_t)N * 32 * 4);
    unsigned* bucketed = (unsigned*)p; p += align16((size_t)NB * CAPB * 4);
    unsigned short* csr = (unsigned short*)p; p += align16((size_t)E * 2);
    int* gcur          = (int*)p; p += align16((size_t)(NB + 1) * 4);
    int* gstart        = (int*)p; p += align16((size_t)(NB + 1) * 4);
    int* rowptr        = (int*)p; p += align16((size_t)(N + 1) * 4);
    float* ssinv       = (float*)p; p += align16((size_t)N * 4);
    float* t           = (float*)p; p += align16((size_t)N * 4);

    const int nb_w4 = (N + 3) / 4;
    const int nb_bkt = (E + 8191) / 8192;
    const int ptotal = L * 64 * 128;
    const int nb_lay = (N + 15) / 16;

    k_initcur<<<(NB + 255) / 256, 256, 0, stream>>>(NB, gcur);
    k_bucket<<<nb_bkt, 256, 0, stream>>>(E, src, dst, gcur, bucketed, NB);
    k_bktscan<<<1, 512, 0, stream>>>(NB, N, gcur, gstart, rowptr);
    k_csr<<<NB, 256, 0, stream>>>(N, bucketed, gcur, gstart, csr, rowptr, ssinv);
    k_prep<<<(ptotal + 255) / 256, 256, 0, stream>>>(ptotal, W_mid, WTh);

    k_in<<<nb_w4, 256, 0, stream>>>(N, x0, rowptr, csr, ssinv, W_in, b_in, xAP);

    for (int l = 0; l < L / 2; ++l) {
        const unsigned short* Wa = WTh + (size_t)(2 * l) * 64 * 128;
        const unsigned short* Wb = WTh + (size_t)(2 * l + 1) * 64 * 128;
        const float* W3a = W_mid + (size_t)(2 * l) * 129 * 64 + 128 * 64;
        const float* W3b = W_mid + (size_t)(2 * l + 1) * 129 * 64 + 128 * 64;

        // x1 = leaky(conv(x2)) : xAP -> xBP
        k_layer<false><<<nb_lay, 256, 0, stream>>>(
            N, xAP, nullptr, xBP, rowptr, csr, ssinv,
            Wa, W3a, b_mid + (size_t)(2 * l) * HDIM);
        // x2 = leaky(conv(x1) + x2) : xBP (+xAP) -> xAP
        k_layer<true><<<nb_lay, 256, 0, stream>>>(
            N, xBP, xAP, xAP, rowptr, csr, ssinv,
            Wb, W3b, b_mid + (size_t)(2 * l + 1) * HDIM);
    }

    k_t<<<nb_w4, 256, 0, stream>>>(N, xAP, W_out + 64, t);
    k_out<<<nb_w4, 256, 0, stream>>>(N, xAP, x0, rowptr, csr, ssinv, t,
                                     W_out, b_out, out);
}

// Round 6
// 332.313 us; speedup vs baseline: 1.9109x; 1.4985x over previous
//
#include <hip/hip_runtime.h>
#include <hip/hip_fp16.h>

#define HDIM 64
#define NEG_SLOPE 0.01f
#define CAPB 8192      // bucketed[] region per 128-node bucket
#define BCAP 6144      // LDS staging capacity in k_csr

typedef _Float16 half8 __attribute__((ext_vector_type(8)));
typedef float f32x4 __attribute__((ext_vector_type(4)));

static __device__ __forceinline__ float h_lo(unsigned d) {
    return __half2float(__ushort_as_half((unsigned short)(d & 0xffffu)));
}
static __device__ __forceinline__ float h_hi(unsigned d) {
    return __half2float(__ushort_as_half((unsigned short)(d >> 16)));
}
static __device__ __forceinline__ unsigned packh(float a, float b) {
    unsigned short ra = __half_as_ushort(__float2half(a));
    unsigned short rb = __half_as_ushort(__float2half(b));
    return ((unsigned)rb << 16) | (unsigned)ra;
}
static __device__ __forceinline__ half8 u4h(uint4 v) {
    union { uint4 u; half8 h; } x; x.u = v; return x.h;
}

__global__ void k_initcur(int NB, int* gcur) {
    int i = blockIdx.x * blockDim.x + threadIdx.x;
    if (i < NB) gcur[i] = i * CAPB;
}

// Phase 1: bucket edges by dst>>7 into fixed regions; packed u32 = (dst<<16)|src.
__global__ void k_bucket(int E, const int* __restrict__ src, const int* __restrict__ dst,
                         int* gcur, unsigned* __restrict__ bucketed, int NB) {
    __shared__ int lh[512];
    __shared__ int lbase[512];
    int t = threadIdx.x;
    int e0 = blockIdx.x * 8192;
    for (int i = t; i < NB; i += 256) lh[i] = 0;
    __syncthreads();
    for (int k = 0; k < 32; ++k) {
        int e = e0 + k * 256 + t;
        if (e < E) atomicAdd(&lh[((unsigned)dst[e]) >> 7], 1);
    }
    __syncthreads();
    for (int i = t; i < NB; i += 256) {
        int c = lh[i];
        lbase[i] = (c > 0) ? atomicAdd(&gcur[i], c) : 0;
        lh[i] = 0;
    }
    __syncthreads();
    for (int k = 0; k < 32; ++k) {
        int e = e0 + k * 256 + t;
        if (e < E) {
            int d = dst[e], s = src[e];
            int b = ((unsigned)d) >> 7;
            int r = atomicAdd(&lh[b], 1);
            int pos = lbase[b] + r;
            if (pos < (b + 1) * CAPB)
                bucketed[pos] = ((unsigned)d << 16) | (unsigned)s;
        }
    }
}

// Exclusive scan of bucket counts -> gstart; rowptr[N].
__global__ void k_bktscan(int NB, int N, const int* __restrict__ gcur,
                          int* gstart, int* rowptr) {
    __shared__ int sd[512];
    int t = threadIdx.x;
    int c = (t < NB) ? min(gcur[t] - t * CAPB, CAPB) : 0;
    sd[t] = c;
    __syncthreads();
    int x = c;
    for (int s = 1; s < 512; s <<= 1) {
        int p = (t >= s) ? sd[t - s] : 0;
        __syncthreads();
        x += p;
        sd[t] = x;
        __syncthreads();
    }
    if (t < NB) gstart[t] = x - c;
    if (t == NB - 1) {
        gstart[NB] = x;
        rowptr[N] = x;
    }
}

// Phase 2: per bucket, LDS hist+scan over 128 local dsts -> rowptr/ssinv + coalesced csr.
__global__ void k_csr(int N, const unsigned* __restrict__ bucketed, const int* __restrict__ gcur,
                      const int* __restrict__ gstart, unsigned short* __restrict__ csr,
                      int* __restrict__ rowptr, float* __restrict__ ssinv) {
    __shared__ unsigned st[BCAP];
    __shared__ int hist[128], cur[128], sgp[128];
    int b = blockIdx.x, t = threadIdx.x;
    int n0 = b << 7;
    int nn = min(128, N - n0);
    int cnt = min(gcur[b] - b * CAPB, CAPB);
    int base = gstart[b];
    if (t < 128) { hist[t] = 0; sgp[t] = 0; }
    __syncthreads();
    bool single = (cnt <= BCAP);
    for (int off = 0; off < cnt; off += BCAP) {
        int bs = min(BCAP, cnt - off);
        for (int i = t; i < bs; i += 256) {
            unsigned w = bucketed[b * CAPB + off + i];
            if (single) st[i] = w;
            int d = (int)(w >> 16);
            int s = (int)(w & 0xffffu);
            int dl = d - n0;
            atomicAdd(&hist[dl], 1);
            atomicAdd(&sgp[dl], ((s < d) ? 1024 : 0) + ((s == d) ? 1 : 0));
        }
    }
    __syncthreads();
    int deg_t = (t < 128) ? hist[t] : 0;
    int x = deg_t;
    for (int s = 1; s < 128; s <<= 1) {
        int p = (t < 128 && t >= s) ? hist[t - s] : 0;
        __syncthreads();
        if (t < 128) { x += p; hist[t] = x; }
        __syncthreads();
    }
    if (t < 128) {
        int excl = hist[t] - deg_t;
        cur[t] = excl;
        if (t < nn) {
            rowptr[n0 + t] = base + excl;
            int sg = sgp[t];
            int lt = sg >> 10, eq = sg & 1023;
            float ss = (float)(deg_t - eq - 2 * lt);
            ssinv[n0 + t] = (deg_t > 0) ? ss / (float)deg_t : 0.f;
        }
    }
    __syncthreads();
    for (int off = 0; off < cnt; off += BCAP) {
        int bs = min(BCAP, cnt - off);
        if (!single) {
            for (int i = t; i < bs; i += 256) st[i] = bucketed[b * CAPB + off + i];
            __syncthreads();
        }
        for (int i = t; i < bs; i += 256) {
            unsigned w = st[i];
            int dl = (int)(w >> 16) - n0;
            int p = atomicAdd(&cur[dl], 1);
            csr[base + p] = (unsigned short)(w & 0xffffu);
        }
        if (!single) __syncthreads();
    }
}

// WTh[l][h][k] fp16: B[k][h] = W[k][h] - (k<64 ? W[64+k][h] : 0)   (k<64: A, k>=64: W2)
__global__ void k_prep(int total, const float* __restrict__ W_mid,
                       unsigned short* __restrict__ WTh) {
    int i = blockIdx.x * blockDim.x + threadIdx.x;
    if (i >= total) return;
    int l = i >> 13;
    int rem = i & 8191;
    int h = rem >> 7;
    int k = rem & 127;
    const float* W = W_mid + (size_t)l * 129 * 64;
    float v = W[k * 64 + h] - ((k < 64) ? W[(64 + k) * 64 + h] : 0.f);
    WTh[i] = __half_as_ushort(__float2half(v));
}

// zero the sentinel row N of both feature buffers (gather target for padded lanes)
__global__ void k_zrow(int N, unsigned* xAP, unsigned* xBP) {
    int t = threadIdx.x;
    if (t < 32) xAP[(size_t)N * 32 + t] = 0u;
    else        xBP[(size_t)N * 32 + (t - 32)] = 0u;
}

// conv_in: x [N,1] fp32 -> packed fp16 [N,32] dwords
__global__ void k_in(int N, const float* __restrict__ x0,
                     const int* __restrict__ rowptr, const unsigned short* __restrict__ csr,
                     const float* __restrict__ ssinv,
                     const float* __restrict__ W_in, const float* __restrict__ b_in,
                     unsigned* __restrict__ xoutP) {
    int wid = blockIdx.x * (blockDim.x >> 6) + (threadIdx.x >> 6);
    int lane = threadIdx.x & 63;
    if (wid >= N) return;
    int beg = rowptr[wid], end = rowptr[wid + 1];
    int deg = end - beg;
    float s = 0.f;
    for (int e = beg + lane; e < end; e += 64) s += x0[csr[e]];
    for (int m = 32; m >= 1; m >>= 1) s += __shfl_xor(s, m, 64);
    float invd = 1.f / (float)max(deg, 1);
    float mean = s * invd;
    float xi = x0[wid];
    float w1 = W_in[lane], w2 = W_in[64 + lane], w3 = W_in[128 + lane];
    float y = xi * (w1 - w2) + mean * w2 + ssinv[wid] * w3 + b_in[lane];
    if (deg == 0) y = 0.f;
    float ylo = __shfl(y, (2 * lane) & 63, 64);
    float yhi = __shfl(y, (2 * lane + 1) & 63, 64);
    unsigned pkd = packh(ylo, yhi);
    if (lane < 32) xoutP[(size_t)wid * 32 + lane] = pkd;
}

// Fused layer: wide-gather mean(x_j) -> LDS A=[x_i|M] fp16 -> MFMA -> epilogue.
// Block = 256 threads = 16 nodes; wave w owns output h-tile [16w,16w+16).
// Gather: 8 lanes per source row (uint4 = 16B each), 8 rows per vmem instr.
template <bool RES>
__global__ __launch_bounds__(256) void k_layer(
        int N, const unsigned* __restrict__ xinP,
        const unsigned* __restrict__ xresP, unsigned* __restrict__ xoutP,
        const int* __restrict__ rowptr, const unsigned short* __restrict__ csr,
        const float* __restrict__ ssinv,
        const unsigned short* __restrict__ WThl,   // [64 h][128 k] fp16
        const float* __restrict__ W3, const float* __restrict__ bias) {
    __shared__ unsigned Ald[16 * 64];   // 16 nodes x 64 dwords (128 f16), XOR-swizzled 16B groups
    __shared__ float Cld[16 * 64];
    __shared__ int sdeg[16];
    __shared__ float sss[16];

    int t = threadIdx.x;
    int lane = t & 63;
    int wv = t >> 6;
    int n0 = blockIdx.x << 4;
    int kg = lane >> 4;

    // B-fragments for this wave's h-tile (16 VGPRs, whole kernel)
    int cb = (wv << 4) + (lane & 15);
    const uint4* wp = (const uint4*)WThl;
    uint4 b0 = wp[cb * 16 + kg + 0];
    uint4 b1 = wp[cb * 16 + kg + 4];
    uint4 b2 = wp[cb * 16 + kg + 8];
    uint4 b3 = wp[cb * 16 + kg + 12];

    const uint4* xin16 = (const uint4*)xinP;
    int sub = lane >> 3;     // which of 8 rows in a group this lane serves
    int lq = lane & 7;       // 16B slice within the 128B row

    // ---- gather phase: wave handles 4 nodes sequentially ----
    for (int q = 0; q < 4; ++q) {
        int nd = (wv << 2) + q;
        int node = n0 + nd;
        float a0 = 0.f, a1 = 0.f, a2 = 0.f, a3 = 0.f;
        float a4 = 0.f, a5 = 0.f, a6 = 0.f, a7 = 0.f;
        int deg = 0;
        float ssv = 0.f;
        uint4 xi4 = make_uint4(0u, 0u, 0u, 0u);
        if (node < N) {
            int beg = __builtin_amdgcn_readfirstlane(rowptr[node]);
            int end = __builtin_amdgcn_readfirstlane(rowptr[node + 1]);
            deg = end - beg;
            for (int tb = beg; tb < end; tb += 64) {
                int cnt = min(64, end - tb);
                int sv = (lane < cnt) ? (int)csr[tb + lane] : N;   // N = zero row
                int ng = (cnt + 7) >> 3;
#pragma unroll 4
                for (int g = 0; g < ng; ++g) {
                    int si = __shfl(sv, (g << 3) + sub, 64);
                    uint4 d = xin16[(size_t)si * 8 + lq];
                    a0 += h_lo(d.x); a1 += h_hi(d.x);
                    a2 += h_lo(d.y); a3 += h_hi(d.y);
                    a4 += h_lo(d.z); a5 += h_hi(d.z);
                    a6 += h_lo(d.w); a7 += h_hi(d.w);
                }
            }
            if (lane < 8) xi4 = xin16[(size_t)node * 8 + lane];
            ssv = ssinv[node];
        }
        // reduce over the 8 sub-groups (keeps lq)
#pragma unroll
        for (int m = 8; m <= 32; m <<= 1) {
            a0 += __shfl_xor(a0, m, 64); a1 += __shfl_xor(a1, m, 64);
            a2 += __shfl_xor(a2, m, 64); a3 += __shfl_xor(a3, m, 64);
            a4 += __shfl_xor(a4, m, 64); a5 += __shfl_xor(a5, m, 64);
            a6 += __shfl_xor(a6, m, 64); a7 += __shfl_xor(a7, m, 64);
        }
        float invd = 1.f / (float)max(deg, 1);
        uint4 mv;
        mv.x = packh(a0 * invd, a1 * invd);
        mv.y = packh(a2 * invd, a3 * invd);
        mv.z = packh(a4 * invd, a5 * invd);
        mv.w = packh(a6 * invd, a7 * invd);
        if (lane < 8) {
            // lane c holds features 8c..8c+7: x_i -> group c, M -> group 8+c (XOR swizzle)
            int gx = lane ^ (nd & 7);
            int gm = (8 + lane) ^ (nd & 7);
            ((uint4*)Ald)[nd * 16 + gx] = xi4;
            ((uint4*)Ald)[nd * 16 + gm] = mv;
        }
        if (lane == 0) { sdeg[nd] = deg; sss[nd] = ssv; }
    }
    __syncthreads();

    // ---- MFMA: C[16 nodes][16 h] = A[16][128] @ B[128][16] ----
    int r = lane & 15;
    const uint4* ap = (const uint4*)Ald;
    int rx = (r & 7);
    uint4 fa0 = ap[r * 16 + ((0 + kg) ^ rx)];
    uint4 fa1 = ap[r * 16 + ((4 + kg) ^ rx)];
    uint4 fa2 = ap[r * 16 + ((8 + kg) ^ rx)];
    uint4 fa3 = ap[r * 16 + ((12 + kg) ^ rx)];
    f32x4 acc = {0.f, 0.f, 0.f, 0.f};
    acc = __builtin_amdgcn_mfma_f32_16x16x32_f16(u4h(fa0), u4h(b0), acc, 0, 0, 0);
    acc = __builtin_amdgcn_mfma_f32_16x16x32_f16(u4h(fa1), u4h(b1), acc, 0, 0, 0);
    acc = __builtin_amdgcn_mfma_f32_16x16x32_f16(u4h(fa2), u4h(b2), acc, 0, 0, 0);
    acc = __builtin_amdgcn_mfma_f32_16x16x32_f16(u4h(fa3), u4h(b3), acc, 0, 0, 0);
#pragma unroll
    for (int reg = 0; reg < 4; ++reg)
        Cld[(kg * 4 + reg) * 64 + (wv << 4) + r] = acc[reg];
    __syncthreads();

    // ---- epilogue: thread t -> node t>>4, dword cols (t&15) and (t&15)+16 ----
    int nd = t >> 4;
    int node = n0 + nd;
    if (node < N) {
        int dg = sdeg[nd];
        float ss = sss[nd];
#pragma unroll
        for (int jj = 0; jj < 2; ++jj) {
            int j = (t & 15) + jj * 16;
            float y0 = Cld[nd * 64 + 2 * j];
            float y1 = Cld[nd * 64 + 2 * j + 1];
            float2 w3 = ((const float2*)W3)[j];
            float2 bb = ((const float2*)bias)[j];
            y0 += ss * w3.x + bb.x;
            y1 += ss * w3.y + bb.y;
            if (dg == 0) { y0 = 0.f; y1 = 0.f; }
            if (RES) {
                unsigned rw = xresP[(size_t)node * 32 + j];
                y0 += h_lo(rw);
                y1 += h_hi(rw);
            }
            y0 = (y0 > 0.f) ? y0 : NEG_SLOPE * y0;
            y1 = (y1 > 0.f) ? y1 : NEG_SLOPE * y1;
            xoutP[(size_t)node * 32 + j] = packh(y0, y1);
        }
    }
}

// t[i] = dot(x'[i], W_out[64:128])
__global__ void k_t(int N, const unsigned* __restrict__ xAP, const float* __restrict__ Wt,
                    float* __restrict__ t) {
    int wid = blockIdx.x * (blockDim.x >> 6) + (threadIdx.x >> 6);
    int lane = threadIdx.x & 63;
    if (wid >= N) return;
    float p = 0.f;
    if (lane < 32) {
        unsigned d = xAP[(size_t)wid * 32 + lane];
        float2 wt = ((const float2*)Wt)[lane];
        p = h_lo(d) * wt.x + h_hi(d) * wt.y;
    }
    for (int m = 32; m >= 1; m >>= 1) p += __shfl_xor(p, m, 64);
    if (lane == 0) t[wid] = p;
}

// conv_out + residual x
__global__ void k_out(int N, const unsigned* __restrict__ xAP, const float* __restrict__ x0,
                      const int* __restrict__ rowptr, const unsigned short* __restrict__ csr,
                      const float* __restrict__ ssinv, const float* __restrict__ t,
                      const float* __restrict__ W_out, const float* __restrict__ b_out,
                      float* __restrict__ out) {
    int wid = blockIdx.x * (blockDim.x >> 6) + (threadIdx.x >> 6);
    int lane = threadIdx.x & 63;
    if (wid >= N) return;
    int beg = rowptr[wid], end = rowptr[wid + 1];
    int deg = end - beg;
    float s = 0.f;
    for (int e = beg + lane; e < end; e += 64) s += t[csr[e]];
    unsigned xw = xAP[(size_t)wid * 32 + (lane >> 1)];
    float xf = (lane & 1) ? h_hi(xw) : h_lo(xw);
    float p = xf * (W_out[lane] - W_out[64 + lane]);
    for (int m = 32; m >= 1; m >>= 1) {
        s += __shfl_xor(s, m, 64);
        p += __shfl_xor(p, m, 64);
    }
    float invd = 1.f / (float)max(deg, 1);
    float y = p + s * invd + ssinv[wid] * W_out[128] + b_out[0];
    if (deg == 0) y = 0.f;
    if (lane == 0) out[wid] = y + x0[wid];
}

static inline size_t align16(size_t x) { return (x + 15) & ~(size_t)15; }

extern "C" void kernel_launch(void* const* d_in, const int* in_sizes, int n_in,
                              void* d_out, int out_size, void* d_ws, size_t ws_size,
                              hipStream_t stream) {
    const float* x0    = (const float*)d_in[0];
    const int*   ei    = (const int*)d_in[1];
    const float* W_in  = (const float*)d_in[2];
    const float* b_in  = (const float*)d_in[3];
    const float* W_mid = (const float*)d_in[4];
    const float* b_mid = (const float*)d_in[5];
    const float* W_out = (const float*)d_in[6];
    const float* b_out = (const float*)d_in[7];
    float* out = (float*)d_out;

    const int N = in_sizes[0];
    const int E = in_sizes[1] / 2;
    const int L = in_sizes[4] / (129 * 64);
    const int NB = (N + 127) >> 7;
    const int* src = ei;
    const int* dst = ei + E;

    char* p = (char*)d_ws;
    unsigned short* WTh = (unsigned short*)p; p += align16((size_t)L * 64 * 128 * 2);
    unsigned* xAP = (unsigned*)p; p += align16((size_t)(N + 1) * 32 * 4);
    unsigned* xBP = (unsigned*)p; p += align16((size_t)(N + 1) * 32 * 4);
    unsigned* bucketed = (unsigned*)p; p += align16((size_t)NB * CAPB * 4);
    unsigned short* csr = (unsigned short*)p; p += align16((size_t)E * 2);
    int* gcur          = (int*)p; p += align16((size_t)(NB + 1) * 4);
    int* gstart        = (int*)p; p += align16((size_t)(NB + 1) * 4);
    int* rowptr        = (int*)p; p += align16((size_t)(N + 1) * 4);
    float* ssinv       = (float*)p; p += align16((size_t)N * 4);
    float* t           = (float*)p; p += align16((size_t)N * 4);

    const int nb_w4 = (N + 3) / 4;
    const int nb_bkt = (E + 8191) / 8192;
    const int ptotal = L * 64 * 128;
    const int nb_lay = (N + 15) / 16;

    k_initcur<<<(NB + 255) / 256, 256, 0, stream>>>(NB, gcur);
    k_bucket<<<nb_bkt, 256, 0, stream>>>(E, src, dst, gcur, bucketed, NB);
    k_bktscan<<<1, 512, 0, stream>>>(NB, N, gcur, gstart, rowptr);
    k_csr<<<NB, 256, 0, stream>>>(N, bucketed, gcur, gstart, csr, rowptr, ssinv);
    k_prep<<<(ptotal + 255) / 256, 256, 0, stream>>>(ptotal, W_mid, WTh);
    k_zrow<<<1, 64, 0, stream>>>(N, xAP, xBP);

    k_in<<<nb_w4, 256, 0, stream>>>(N, x0, rowptr, csr, ssinv, W_in, b_in, xAP);

    for (int l = 0; l < L / 2; ++l) {
        const unsigned short* Wa = WTh + (size_t)(2 * l) * 64 * 128;
        const unsigned short* Wb = WTh + (size_t)(2 * l + 1) * 64 * 128;
        const float* W3a = W_mid + (size_t)(2 * l) * 129 * 64 + 128 * 64;
        const float* W3b = W_mid + (size_t)(2 * l + 1) * 129 * 64 + 128 * 64;

        // x1 = leaky(conv(x2)) : xAP -> xBP
        k_layer<false><<<nb_lay, 256, 0, stream>>>(
            N, xAP, nullptr, xBP, rowptr, csr, ssinv,
            Wa, W3a, b_mid + (size_t)(2 * l) * HDIM);
        // x2 = leaky(conv(x1) + x2) : xBP (+xAP) -> xAP
        k_layer<true><<<nb_lay, 256, 0, stream>>>(
            N, xBP, xAP, xAP, rowptr, csr, ssinv,
            Wb, W3b, b_mid + (size_t)(2 * l + 1) * HDIM);
    }

    k_t<<<nb_w4, 256, 0, stream>>>(N, xAP, W_out + 64, t);
    k_out<<<nb_w4, 256, 0, stream>>>(N, xAP, x0, rowptr, csr, ssinv, t,
                                     W_out, b_out, out);
}

// Round 7
// 288.483 us; speedup vs baseline: 2.2012x; 1.1519x over previous
//
#include <hip/hip_runtime.h>
#include <hip/hip_fp16.h>

#define HDIM 64
#define NEG_SLOPE 0.01f
#define CAPB 8192      // bucketed[] region per 128-node bucket
#define BCAP 6144      // LDS staging capacity in k_csr

typedef _Float16 half8 __attribute__((ext_vector_type(8)));
typedef float f32x4 __attribute__((ext_vector_type(4)));

static __device__ __forceinline__ float h_lo(unsigned d) {
    return __half2float(__ushort_as_half((unsigned short)(d & 0xffffu)));
}
static __device__ __forceinline__ float h_hi(unsigned d) {
    return __half2float(__ushort_as_half((unsigned short)(d >> 16)));
}
static __device__ __forceinline__ unsigned packh(float a, float b) {
    unsigned short ra = __half_as_ushort(__float2half(a));
    unsigned short rb = __half_as_ushort(__float2half(b));
    return ((unsigned)rb << 16) | (unsigned)ra;
}
static __device__ __forceinline__ half8 u4h(uint4 v) {
    union { uint4 u; half8 h; } x; x.u = v; return x.h;
}
static __device__ __forceinline__ __half2 uh2(unsigned u) {
    union { unsigned u; __half2 h; } x; x.u = u; return x.h;
}
static __device__ __forceinline__ unsigned h2u(__half2 h) {
    union { __half2 h; unsigned u; } x; x.h = h; return x.u;
}
static __device__ __forceinline__ __half2 hsum8(unsigned a, unsigned b, unsigned c, unsigned d,
                                                unsigned e, unsigned f, unsigned g, unsigned h) {
    __half2 p0 = __hadd2(uh2(a), uh2(b));
    __half2 p1 = __hadd2(uh2(c), uh2(d));
    __half2 p2 = __hadd2(uh2(e), uh2(f));
    __half2 p3 = __hadd2(uh2(g), uh2(h));
    return __hadd2(__hadd2(p0, p1), __hadd2(p2, p3));
}

__global__ void k_initcur(int NB, int* gcur) {
    int i = blockIdx.x * blockDim.x + threadIdx.x;
    if (i < NB) gcur[i] = i * CAPB;
}

// Phase 1: bucket edges by dst>>7 into fixed regions; packed u32 = (dst<<16)|src.
// 2048 edges/block for occupancy.
__global__ void k_bucket(int E, const int* __restrict__ src, const int* __restrict__ dst,
                         int* gcur, unsigned* __restrict__ bucketed, int NB) {
    __shared__ int lh[512];
    __shared__ int lbase[512];
    int t = threadIdx.x;
    int e0 = blockIdx.x * 2048;
    for (int i = t; i < NB; i += 256) lh[i] = 0;
    __syncthreads();
    for (int k = 0; k < 8; ++k) {
        int e = e0 + k * 256 + t;
        if (e < E) atomicAdd(&lh[((unsigned)dst[e]) >> 7], 1);
    }
    __syncthreads();
    for (int i = t; i < NB; i += 256) {
        int c = lh[i];
        lbase[i] = (c > 0) ? atomicAdd(&gcur[i], c) : 0;
        lh[i] = 0;
    }
    __syncthreads();
    for (int k = 0; k < 8; ++k) {
        int e = e0 + k * 256 + t;
        if (e < E) {
            int d = dst[e], s = src[e];
            int b = ((unsigned)d) >> 7;
            int r = atomicAdd(&lh[b], 1);
            int pos = lbase[b] + r;
            if (pos < (b + 1) * CAPB)
                bucketed[pos] = ((unsigned)d << 16) | (unsigned)s;
        }
    }
}

// Exclusive scan of bucket counts -> gstart; rowptr[N].
__global__ void k_bktscan(int NB, int N, const int* __restrict__ gcur,
                          int* gstart, int* rowptr) {
    __shared__ int sd[512];
    int t = threadIdx.x;
    int c = (t < NB) ? min(gcur[t] - t * CAPB, CAPB) : 0;
    sd[t] = c;
    __syncthreads();
    int x = c;
    for (int s = 1; s < 512; s <<= 1) {
        int p = (t >= s) ? sd[t - s] : 0;
        __syncthreads();
        x += p;
        sd[t] = x;
        __syncthreads();
    }
    if (t < NB) gstart[t] = x - c;
    if (t == NB - 1) {
        gstart[NB] = x;
        rowptr[N] = x;
    }
}

// Phase 2: per bucket, LDS hist+scan over 128 local dsts -> rowptr/ssinv,
// exact csr AND padded pcsr (64 slots/node, sentinel N).
__global__ void k_csr(int N, const unsigned* __restrict__ bucketed, const int* __restrict__ gcur,
                      const int* __restrict__ gstart, unsigned short* __restrict__ csr,
                      unsigned short* __restrict__ pcsr,
                      int* __restrict__ rowptr, float* __restrict__ ssinv) {
    __shared__ unsigned st[BCAP];
    __shared__ int hist[128], cur[128], excl[128], sgp[128];
    int b = blockIdx.x, t = threadIdx.x;
    int n0 = b << 7;
    int nn = min(128, N - n0);
    int cnt = min(gcur[b] - b * CAPB, CAPB);
    int base = gstart[b];
    if (t < 128) { hist[t] = 0; sgp[t] = 0; }
    // init this bucket's padded-csr region (128 nodes x 64 slots) to sentinel N
    unsigned sent = ((unsigned)N << 16) | (unsigned)N;
    unsigned* pb32 = (unsigned*)(pcsr + ((size_t)b << 13));
    for (int i = t; i < 4096; i += 256) pb32[i] = sent;
    __syncthreads();
    bool single = (cnt <= BCAP);
    for (int off = 0; off < cnt; off += BCAP) {
        int bs = min(BCAP, cnt - off);
        for (int i = t; i < bs; i += 256) {
            unsigned w = bucketed[b * CAPB + off + i];
            if (single) st[i] = w;
            int d = (int)(w >> 16);
            int s = (int)(w & 0xffffu);
            int dl = d - n0;
            atomicAdd(&hist[dl], 1);
            atomicAdd(&sgp[dl], ((s < d) ? 1024 : 0) + ((s == d) ? 1 : 0));
        }
    }
    __syncthreads();
    int deg_t = (t < 128) ? hist[t] : 0;
    int x = deg_t;
    for (int s = 1; s < 128; s <<= 1) {
        int p = (t < 128 && t >= s) ? hist[t - s] : 0;
        __syncthreads();
        if (t < 128) { x += p; hist[t] = x; }
        __syncthreads();
    }
    if (t < 128) {
        int ex = hist[t] - deg_t;
        excl[t] = ex;
        cur[t] = ex;
        if (t < nn) {
            rowptr[n0 + t] = base + ex;
            int sg = sgp[t];
            int lt = sg >> 10, eq = sg & 1023;
            float ss = (float)(deg_t - eq - 2 * lt);
            ssinv[n0 + t] = (deg_t > 0) ? ss / (float)deg_t : 0.f;
        }
    }
    __syncthreads();
    for (int off = 0; off < cnt; off += BCAP) {
        int bs = min(BCAP, cnt - off);
        if (!single) {
            for (int i = t; i < bs; i += 256) st[i] = bucketed[b * CAPB + off + i];
            __syncthreads();
        }
        for (int i = t; i < bs; i += 256) {
            unsigned w = st[i];
            int dl = (int)(w >> 16) - n0;
            unsigned short sval = (unsigned short)(w & 0xffffu);
            int p = atomicAdd(&cur[dl], 1);
            csr[base + p] = sval;
            int r = p - excl[dl];
            if (r < 64) pcsr[((size_t)(n0 + dl) << 6) + r] = sval;
        }
        if (!single) __syncthreads();
    }
}

// WTh[l][h][k] fp16: B[k][h] = W[k][h] - (k<64 ? W[64+k][h] : 0)   (k<64: A, k>=64: W2)
__global__ void k_prep(int total, const float* __restrict__ W_mid,
                       unsigned short* __restrict__ WTh) {
    int i = blockIdx.x * blockDim.x + threadIdx.x;
    if (i >= total) return;
    int l = i >> 13;
    int rem = i & 8191;
    int h = rem >> 7;
    int k = rem & 127;
    const float* W = W_mid + (size_t)l * 129 * 64;
    float v = W[k * 64 + h] - ((k < 64) ? W[(64 + k) * 64 + h] : 0.f);
    WTh[i] = __half_as_ushort(__float2half(v));
}

// zero the sentinel row N of both feature buffers (gather target for padded lanes)
__global__ void k_zrow(int N, unsigned* xAP, unsigned* xBP) {
    int t = threadIdx.x;
    if (t < 32) xAP[(size_t)N * 32 + t] = 0u;
    else        xBP[(size_t)N * 32 + (t - 32)] = 0u;
}

// conv_in: x [N,1] fp32 -> packed fp16 [N,32] dwords
__global__ void k_in(int N, const float* __restrict__ x0,
                     const int* __restrict__ rowptr, const unsigned short* __restrict__ csr,
                     const float* __restrict__ ssinv,
                     const float* __restrict__ W_in, const float* __restrict__ b_in,
                     unsigned* __restrict__ xoutP) {
    int wid = blockIdx.x * (blockDim.x >> 6) + (threadIdx.x >> 6);
    int lane = threadIdx.x & 63;
    if (wid >= N) return;
    int beg = rowptr[wid], end = rowptr[wid + 1];
    int deg = end - beg;
    float s = 0.f;
    for (int e = beg + lane; e < end; e += 64) s += x0[csr[e]];
    for (int m = 32; m >= 1; m >>= 1) s += __shfl_xor(s, m, 64);
    float invd = 1.f / (float)max(deg, 1);
    float mean = s * invd;
    float xi = x0[wid];
    float w1 = W_in[lane], w2 = W_in[64 + lane], w3 = W_in[128 + lane];
    float y = xi * (w1 - w2) + mean * w2 + ssinv[wid] * w3 + b_in[lane];
    if (deg == 0) y = 0.f;
    float ylo = __shfl(y, (2 * lane) & 63, 64);
    float yhi = __shfl(y, (2 * lane + 1) & 63, 64);
    unsigned pkd = packh(ylo, yhi);
    if (lane < 32) xoutP[(size_t)wid * 32 + lane] = pkd;
}

// Fused layer: branch-free padded gather (fp16 pk accumulate) -> LDS A=[x_i|M] -> MFMA -> epilogue.
// Block = 256 threads = 16 nodes; wave w owns output h-tile [16w,16w+16).
template <bool RES>
__global__ __launch_bounds__(256) void k_layer(
        int N, const unsigned* __restrict__ xinP,
        const unsigned* __restrict__ xresP, unsigned* __restrict__ xoutP,
        const int* __restrict__ rowptr, const unsigned short* __restrict__ csr,
        const unsigned short* __restrict__ pcsr,
        const float* __restrict__ ssinv,
        const unsigned short* __restrict__ WThl,   // [64 h][128 k] fp16
        const float* __restrict__ W3, const float* __restrict__ bias) {
    __shared__ unsigned Ald[16 * 64];   // 16 nodes x 64 dwords (128 f16), XOR-swizzled 16B groups
    __shared__ float Cld[16 * 64];
    __shared__ int sdeg[16];
    __shared__ float sss[16];

    int t = threadIdx.x;
    int lane = t & 63;
    int wv = t >> 6;
    int n0 = blockIdx.x << 4;
    int kg = lane >> 4;

    // B-fragments for this wave's h-tile (16 VGPRs, whole kernel)
    int cb = (wv << 4) + (lane & 15);
    const uint4* wp = (const uint4*)WThl;
    uint4 b0 = wp[cb * 16 + kg + 0];
    uint4 b1 = wp[cb * 16 + kg + 4];
    uint4 b2 = wp[cb * 16 + kg + 8];
    uint4 b3 = wp[cb * 16 + kg + 12];

    const uint4* xin16 = (const uint4*)xinP;
    int sub = lane >> 3;     // which of 8 rows in a group this lane serves
    int lq = lane & 7;       // 16B slice within the 128B row
    int ndb = wv << 2;

    // preload padded-csr rows for all 4 nodes (in-bounds even past N; sentinel-filled)
    int svp[4];
#pragma unroll
    for (int q = 0; q < 4; ++q)
        svp[q] = (int)pcsr[((size_t)(n0 + ndb + q) << 6) + lane];

    // ---- gather phase: wave handles 4 nodes sequentially ----
#pragma unroll
    for (int q = 0; q < 4; ++q) {
        int nd = ndb + q;
        int node = n0 + nd;
        float a0 = 0.f, a1 = 0.f, a2 = 0.f, a3 = 0.f;
        float a4 = 0.f, a5 = 0.f, a6 = 0.f, a7 = 0.f;
        int deg = 0;
        float ssv = 0.f;
        uint4 xi4 = make_uint4(0u, 0u, 0u, 0u);
        if (node < N) {
            int beg = __builtin_amdgcn_readfirstlane(rowptr[node]);
            int end = __builtin_amdgcn_readfirstlane(rowptr[node + 1]);
            deg = end - beg;
            if (lane < 8) xi4 = xin16[(size_t)node * 8 + lane];
            ssv = ssinv[node];
            if (deg <= 64) {
                // branch-free: 8 bpermutes, 8 independent uint4 loads, packed-fp16 accumulate
                int sv = svp[q];
                int s0 = __shfl(sv, sub, 64);
                int s1 = __shfl(sv, 8 + sub, 64);
                int s2 = __shfl(sv, 16 + sub, 64);
                int s3 = __shfl(sv, 24 + sub, 64);
                int s4 = __shfl(sv, 32 + sub, 64);
                int s5 = __shfl(sv, 40 + sub, 64);
                int s6 = __shfl(sv, 48 + sub, 64);
                int s7 = __shfl(sv, 56 + sub, 64);
                uint4 d0 = xin16[(size_t)s0 * 8 + lq];
                uint4 d1 = xin16[(size_t)s1 * 8 + lq];
                uint4 d2 = xin16[(size_t)s2 * 8 + lq];
                uint4 d3 = xin16[(size_t)s3 * 8 + lq];
                uint4 d4 = xin16[(size_t)s4 * 8 + lq];
                uint4 d5 = xin16[(size_t)s5 * 8 + lq];
                uint4 d6 = xin16[(size_t)s6 * 8 + lq];
                uint4 d7 = xin16[(size_t)s7 * 8 + lq];
                unsigned u0 = h2u(hsum8(d0.x, d1.x, d2.x, d3.x, d4.x, d5.x, d6.x, d7.x));
                unsigned u1 = h2u(hsum8(d0.y, d1.y, d2.y, d3.y, d4.y, d5.y, d6.y, d7.y));
                unsigned u2 = h2u(hsum8(d0.z, d1.z, d2.z, d3.z, d4.z, d5.z, d6.z, d7.z));
                unsigned u3 = h2u(hsum8(d0.w, d1.w, d2.w, d3.w, d4.w, d5.w, d6.w, d7.w));
                // packed cross-lane reduce over the 8 sub-groups
#pragma unroll
                for (int m = 8; m <= 32; m <<= 1) {
                    u0 = h2u(__hadd2(uh2(u0), uh2((unsigned)__shfl_xor((int)u0, m, 64))));
                    u1 = h2u(__hadd2(uh2(u1), uh2((unsigned)__shfl_xor((int)u1, m, 64))));
                    u2 = h2u(__hadd2(uh2(u2), uh2((unsigned)__shfl_xor((int)u2, m, 64))));
                    u3 = h2u(__hadd2(uh2(u3), uh2((unsigned)__shfl_xor((int)u3, m, 64))));
                }
                a0 = __half2float(__low2half(uh2(u0)));
                a1 = __half2float(__high2half(uh2(u0)));
                a2 = __half2float(__low2half(uh2(u1)));
                a3 = __half2float(__high2half(uh2(u1)));
                a4 = __half2float(__low2half(uh2(u2)));
                a5 = __half2float(__high2half(uh2(u2)));
                a6 = __half2float(__low2half(uh2(u3)));
                a7 = __half2float(__high2half(uh2(u3)));
            } else {
                // rare fallback: exact csr, guarded loads, f32 accumulate
                for (int tb = beg; tb < end; tb += 64) {
                    int cnt = min(64, end - tb);
                    int sv = (lane < cnt) ? (int)csr[tb + lane] : N;
                    int ng = (cnt + 7) >> 3;
                    for (int g = 0; g < ng; ++g) {
                        int si = __shfl(sv, (g << 3) + sub, 64);
                        uint4 d = xin16[(size_t)si * 8 + lq];
                        a0 += h_lo(d.x); a1 += h_hi(d.x);
                        a2 += h_lo(d.y); a3 += h_hi(d.y);
                        a4 += h_lo(d.z); a5 += h_hi(d.z);
                        a6 += h_lo(d.w); a7 += h_hi(d.w);
                    }
                }
#pragma unroll
                for (int m = 8; m <= 32; m <<= 1) {
                    a0 += __shfl_xor(a0, m, 64); a1 += __shfl_xor(a1, m, 64);
                    a2 += __shfl_xor(a2, m, 64); a3 += __shfl_xor(a3, m, 64);
                    a4 += __shfl_xor(a4, m, 64); a5 += __shfl_xor(a5, m, 64);
                    a6 += __shfl_xor(a6, m, 64); a7 += __shfl_xor(a7, m, 64);
                }
            }
        }
        float invd = 1.f / (float)max(deg, 1);
        uint4 mv;
        mv.x = packh(a0 * invd, a1 * invd);
        mv.y = packh(a2 * invd, a3 * invd);
        mv.z = packh(a4 * invd, a5 * invd);
        mv.w = packh(a6 * invd, a7 * invd);
        if (lane < 8) {
            // lane c holds features 8c..8c+7: x_i -> group c, M -> group 8+c (XOR swizzle)
            int gx = lane ^ (nd & 7);
            int gm = (8 + lane) ^ (nd & 7);
            ((uint4*)Ald)[nd * 16 + gx] = xi4;
            ((uint4*)Ald)[nd * 16 + gm] = mv;
        }
        if (lane == 0) { sdeg[nd] = deg; sss[nd] = ssv; }
    }
    __syncthreads();

    // ---- MFMA: C[16 nodes][16 h] = A[16][128] @ B[128][16] ----
    int r = lane & 15;
    const uint4* ap = (const uint4*)Ald;
    int rx = (r & 7);
    uint4 fa0 = ap[r * 16 + ((0 + kg) ^ rx)];
    uint4 fa1 = ap[r * 16 + ((4 + kg) ^ rx)];
    uint4 fa2 = ap[r * 16 + ((8 + kg) ^ rx)];
    uint4 fa3 = ap[r * 16 + ((12 + kg) ^ rx)];
    f32x4 acc = {0.f, 0.f, 0.f, 0.f};
    acc = __builtin_amdgcn_mfma_f32_16x16x32_f16(u4h(fa0), u4h(b0), acc, 0, 0, 0);
    acc = __builtin_amdgcn_mfma_f32_16x16x32_f16(u4h(fa1), u4h(b1), acc, 0, 0, 0);
    acc = __builtin_amdgcn_mfma_f32_16x16x32_f16(u4h(fa2), u4h(b2), acc, 0, 0, 0);
    acc = __builtin_amdgcn_mfma_f32_16x16x32_f16(u4h(fa3), u4h(b3), acc, 0, 0, 0);
#pragma unroll
    for (int reg = 0; reg < 4; ++reg)
        Cld[(kg * 4 + reg) * 64 + (wv << 4) + r] = acc[reg];
    __syncthreads();

    // ---- epilogue: thread t -> node t>>4, dword cols (t&15) and (t&15)+16 ----
    int nd = t >> 4;
    int node = n0 + nd;
    if (node < N) {
        int dg = sdeg[nd];
        float ss = sss[nd];
#pragma unroll
        for (int jj = 0; jj < 2; ++jj) {
            int j = (t & 15) + jj * 16;
            float y0 = Cld[nd * 64 + 2 * j];
            float y1 = Cld[nd * 64 + 2 * j + 1];
            float2 w3 = ((const float2*)W3)[j];
            float2 bb = ((const float2*)bias)[j];
            y0 += ss * w3.x + bb.x;
            y1 += ss * w3.y + bb.y;
            if (dg == 0) { y0 = 0.f; y1 = 0.f; }
            if (RES) {
                unsigned rw = xresP[(size_t)node * 32 + j];
                y0 += h_lo(rw);
                y1 += h_hi(rw);
            }
            y0 = (y0 > 0.f) ? y0 : NEG_SLOPE * y0;
            y1 = (y1 > 0.f) ? y1 : NEG_SLOPE * y1;
            xoutP[(size_t)node * 32 + j] = packh(y0, y1);
        }
    }
}

// t[i] = dot(x'[i], W_out[64:128])
__global__ void k_t(int N, const unsigned* __restrict__ xAP, const float* __restrict__ Wt,
                    float* __restrict__ t) {
    int wid = blockIdx.x * (blockDim.x >> 6) + (threadIdx.x >> 6);
    int lane = threadIdx.x & 63;
    if (wid >= N) return;
    float p = 0.f;
    if (lane < 32) {
        unsigned d = xAP[(size_t)wid * 32 + lane];
        float2 wt = ((const float2*)Wt)[lane];
        p = h_lo(d) * wt.x + h_hi(d) * wt.y;
    }
    for (int m = 32; m >= 1; m >>= 1) p += __shfl_xor(p, m, 64);
    if (lane == 0) t[wid] = p;
}

// conv_out + residual x
__global__ void k_out(int N, const unsigned* __restrict__ xAP, const float* __restrict__ x0,
                      const int* __restrict__ rowptr, const unsigned short* __restrict__ csr,
                      const float* __restrict__ ssinv, const float* __restrict__ t,
                      const float* __restrict__ W_out, const float* __restrict__ b_out,
                      float* __restrict__ out) {
    int wid = blockIdx.x * (blockDim.x >> 6) + (threadIdx.x >> 6);
    int lane = threadIdx.x & 63;
    if (wid >= N) return;
    int beg = rowptr[wid], end = rowptr[wid + 1];
    int deg = end - beg;
    float s = 0.f;
    for (int e = beg + lane; e < end; e += 64) s += t[csr[e]];
    unsigned xw = xAP[(size_t)wid * 32 + (lane >> 1)];
    float xf = (lane & 1) ? h_hi(xw) : h_lo(xw);
    float p = xf * (W_out[lane] - W_out[64 + lane]);
    for (int m = 32; m >= 1; m >>= 1) {
        s += __shfl_xor(s, m, 64);
        p += __shfl_xor(p, m, 64);
    }
    float invd = 1.f / (float)max(deg, 1);
    float y = p + s * invd + ssinv[wid] * W_out[128] + b_out[0];
    if (deg == 0) y = 0.f;
    if (lane == 0) out[wid] = y + x0[wid];
}

static inline size_t align16(size_t x) { return (x + 15) & ~(size_t)15; }

extern "C" void kernel_launch(void* const* d_in, const int* in_sizes, int n_in,
                              void* d_out, int out_size, void* d_ws, size_t ws_size,
                              hipStream_t stream) {
    const float* x0    = (const float*)d_in[0];
    const int*   ei    = (const int*)d_in[1];
    const float* W_in  = (const float*)d_in[2];
    const float* b_in  = (const float*)d_in[3];
    const float* W_mid = (const float*)d_in[4];
    const float* b_mid = (const float*)d_in[5];
    const float* W_out = (const float*)d_in[6];
    const float* b_out = (const float*)d_in[7];
    float* out = (float*)d_out;

    const int N = in_sizes[0];
    const int E = in_sizes[1] / 2;
    const int L = in_sizes[4] / (129 * 64);
    const int NB = (N + 127) >> 7;
    const int* src = ei;
    const int* dst = ei + E;

    char* p = (char*)d_ws;
    unsigned short* WTh = (unsigned short*)p; p += align16((size_t)L * 64 * 128 * 2);
    unsigned* xAP = (unsigned*)p; p += align16((size_t)(N + 1) * 32 * 4);
    unsigned* xBP = (unsigned*)p; p += align16((size_t)(N + 1) * 32 * 4);
    unsigned* bucketed = (unsigned*)p; p += align16((size_t)NB * CAPB * 4);
    unsigned short* csr = (unsigned short*)p; p += align16((size_t)E * 2);
    unsigned short* pcsr = (unsigned short*)p; p += align16((size_t)NB * 8192 * 2);
    int* gcur          = (int*)p; p += align16((size_t)(NB + 1) * 4);
    int* gstart        = (int*)p; p += align16((size_t)(NB + 1) * 4);
    int* rowptr        = (int*)p; p += align16((size_t)(N + 1) * 4);
    float* ssinv       = (float*)p; p += align16((size_t)N * 4);
    float* t           = (float*)p; p += align16((size_t)N * 4);

    const int nb_w4 = (N + 3) / 4;
    const int nb_bkt = (E + 2047) / 2048;
    const int ptotal = L * 64 * 128;
    const int nb_lay = (N + 15) / 16;

    k_initcur<<<(NB + 255) / 256, 256, 0, stream>>>(NB, gcur);
    k_bucket<<<nb_bkt, 256, 0, stream>>>(E, src, dst, gcur, bucketed, NB);
    k_bktscan<<<1, 512, 0, stream>>>(NB, N, gcur, gstart, rowptr);
    k_csr<<<NB, 256, 0, stream>>>(N, bucketed, gcur, gstart, csr, pcsr, rowptr, ssinv);
    k_prep<<<(ptotal + 255) / 256, 256, 0, stream>>>(ptotal, W_mid, WTh);
    k_zrow<<<1, 64, 0, stream>>>(N, xAP, xBP);

    k_in<<<nb_w4, 256, 0, stream>>>(N, x0, rowptr, csr, ssinv, W_in, b_in, xAP);

    for (int l = 0; l < L / 2; ++l) {
        const unsigned short* Wa = WTh + (size_t)(2 * l) * 64 * 128;
        const unsigned short* Wb = WTh + (size_t)(2 * l + 1) * 64 * 128;
        const float* W3a = W_mid + (size_t)(2 * l) * 129 * 64 + 128 * 64;
        const float* W3b = W_mid + (size_t)(2 * l + 1) * 129 * 64 + 128 * 64;

        // x1 = leaky(conv(x2)) : xAP -> xBP
        k_layer<false><<<nb_lay, 256, 0, stream>>>(
            N, xAP, nullptr, xBP, rowptr, csr, pcsr, ssinv,
            Wa, W3a, b_mid + (size_t)(2 * l) * HDIM);
        // x2 = leaky(conv(x1) + x2) : xBP (+xAP) -> xAP
        k_layer<true><<<nb_lay, 256, 0, stream>>>(
            N, xBP, xAP, xAP, rowptr, csr, pcsr, ssinv,
            Wb, W3b, b_mid + (size_t)(2 * l + 1) * HDIM);
    }

    k_t<<<nb_w4, 256, 0, stream>>>(N, xAP, W_out + 64, t);
    k_out<<<nb_w4, 256, 0, stream>>>(N, xAP, x0, rowptr, csr, ssinv, t,
                                     W_out, b_out, out);
}

// Round 8
// 270.348 us; speedup vs baseline: 2.3488x; 1.0671x over previous
//
#include <hip/hip_runtime.h>
#include <hip/hip_fp16.h>

#define HDIM 64
#define NEG_SLOPE 0.01f
#define CAPB 8192      // bucketed[] region per 128-node bucket
#define BCAP 6144      // LDS staging capacity in k_csr

typedef _Float16 half8 __attribute__((ext_vector_type(8)));
typedef float f32x4 __attribute__((ext_vector_type(4)));

static __device__ __forceinline__ float h_lo(unsigned d) {
    return __half2float(__ushort_as_half((unsigned short)(d & 0xffffu)));
}
static __device__ __forceinline__ float h_hi(unsigned d) {
    return __half2float(__ushort_as_half((unsigned short)(d >> 16)));
}
static __device__ __forceinline__ unsigned packh(float a, float b) {
    unsigned short ra = __half_as_ushort(__float2half(a));
    unsigned short rb = __half_as_ushort(__float2half(b));
    return ((unsigned)rb << 16) | (unsigned)ra;
}
static __device__ __forceinline__ half8 u4h(uint4 v) {
    union { uint4 u; half8 h; } x; x.u = v; return x.h;
}
static __device__ __forceinline__ __half2 uh2(unsigned u) {
    union { unsigned u; __half2 h; } x; x.u = u; return x.h;
}
static __device__ __forceinline__ unsigned h2u(__half2 h) {
    union { __half2 h; unsigned u; } x; x.h = h; return x.u;
}
static __device__ __forceinline__ __half2 hsum8(unsigned a, unsigned b, unsigned c, unsigned d,
                                                unsigned e, unsigned f, unsigned g, unsigned h) {
    __half2 p0 = __hadd2(uh2(a), uh2(b));
    __half2 p1 = __hadd2(uh2(c), uh2(d));
    __half2 p2 = __hadd2(uh2(e), uh2(f));
    __half2 p3 = __hadd2(uh2(g), uh2(h));
    return __hadd2(__hadd2(p0, p1), __hadd2(p2, p3));
}

// merged setup: WTh prep + gcur init + sentinel feature rows
__global__ void k_setup(int ptotal, const float* __restrict__ W_mid,
                        unsigned short* __restrict__ WTh,
                        int NB, int* gcur, int N, unsigned* xAP, unsigned* xBP) {
    int i = blockIdx.x * blockDim.x + threadIdx.x;
    if (i < ptotal) {
        int l = i >> 13;
        int rem = i & 8191;
        int h = rem >> 7;
        int k = rem & 127;
        const float* W = W_mid + (size_t)l * 129 * 64;
        float v = W[k * 64 + h] - ((k < 64) ? W[(64 + k) * 64 + h] : 0.f);
        WTh[i] = __half_as_ushort(__float2half(v));
    }
    if (i < NB) gcur[i] = i * CAPB;
    if (i < 32) xAP[(size_t)N * 32 + i] = 0u;
    else if (i < 64) xBP[(size_t)N * 32 + (i - 32)] = 0u;
}

// Phase 1: bucket edges by dst>>7; loads hoisted into registers ahead of atomic chains.
__global__ void k_bucket(int E, const int* __restrict__ src, const int* __restrict__ dst,
                         int* gcur, unsigned* __restrict__ bucketed, int NB) {
    __shared__ int lh[512];
    __shared__ int lbase[512];
    int t = threadIdx.x;
    int e0 = blockIdx.x * 2048;
    for (int i = t; i < NB; i += 256) lh[i] = 0;
    __syncthreads();
    int dv[8];
#pragma unroll
    for (int k = 0; k < 8; ++k) {
        int e = e0 + k * 256 + t;
        dv[k] = (e < E) ? dst[e] : -1;
    }
#pragma unroll
    for (int k = 0; k < 8; ++k)
        if (dv[k] >= 0) atomicAdd(&lh[((unsigned)dv[k]) >> 7], 1);
    __syncthreads();
    for (int i = t; i < NB; i += 256) {
        int c = lh[i];
        lbase[i] = (c > 0) ? atomicAdd(&gcur[i], c) : 0;
        lh[i] = 0;
    }
    __syncthreads();
    int sv[8];
#pragma unroll
    for (int k = 0; k < 8; ++k) {
        int e = e0 + k * 256 + t;
        sv[k] = (e < E) ? src[e] : 0;
    }
#pragma unroll
    for (int k = 0; k < 8; ++k) {
        if (dv[k] >= 0) {
            int b = ((unsigned)dv[k]) >> 7;
            int r = atomicAdd(&lh[b], 1);
            int pos = lbase[b] + r;
            if (pos < (b + 1) * CAPB)
                bucketed[pos] = ((unsigned)dv[k] << 16) | (unsigned)sv[k];
        }
    }
}

// Exclusive scan of bucket counts -> gstart; rowptr[N].
__global__ void k_bktscan(int NB, int N, const int* __restrict__ gcur,
                          int* gstart, int* rowptr) {
    __shared__ int sd[512];
    int t = threadIdx.x;
    int c = (t < NB) ? min(gcur[t] - t * CAPB, CAPB) : 0;
    sd[t] = c;
    __syncthreads();
    int x = c;
    for (int s = 1; s < 512; s <<= 1) {
        int p = (t >= s) ? sd[t - s] : 0;
        __syncthreads();
        x += p;
        sd[t] = x;
        __syncthreads();
    }
    if (t < NB) gstart[t] = x - c;
    if (t == NB - 1) {
        gstart[NB] = x;
        rowptr[N] = x;
    }
}

// Phase 2: per bucket, LDS hist+scan -> rowptr/ssinv, exact csr AND padded pcsr.
__global__ void k_csr(int N, const unsigned* __restrict__ bucketed, const int* __restrict__ gcur,
                      const int* __restrict__ gstart, unsigned short* __restrict__ csr,
                      unsigned short* __restrict__ pcsr,
                      int* __restrict__ rowptr, float* __restrict__ ssinv) {
    __shared__ unsigned st[BCAP];
    __shared__ int hist[128], cur[128], excl[128], sgp[128];
    int b = blockIdx.x, t = threadIdx.x;
    int n0 = b << 7;
    int nn = min(128, N - n0);
    int cnt = min(gcur[b] - b * CAPB, CAPB);
    int base = gstart[b];
    if (t < 128) { hist[t] = 0; sgp[t] = 0; }
    unsigned sent = ((unsigned)N << 16) | (unsigned)N;
    unsigned* pb32 = (unsigned*)(pcsr + ((size_t)b << 13));
    for (int i = t; i < 4096; i += 256) pb32[i] = sent;
    __syncthreads();
    bool single = (cnt <= BCAP);
    for (int off = 0; off < cnt; off += BCAP) {
        int bs = min(BCAP, cnt - off);
        for (int i = t; i < bs; i += 256) {
            unsigned w = bucketed[b * CAPB + off + i];
            if (single) st[i] = w;
            int d = (int)(w >> 16);
            int s = (int)(w & 0xffffu);
            int dl = d - n0;
            atomicAdd(&hist[dl], 1);
            atomicAdd(&sgp[dl], ((s < d) ? 1024 : 0) + ((s == d) ? 1 : 0));
        }
    }
    __syncthreads();
    int deg_t = (t < 128) ? hist[t] : 0;
    int x = deg_t;
    for (int s = 1; s < 128; s <<= 1) {
        int p = (t < 128 && t >= s) ? hist[t - s] : 0;
        __syncthreads();
        if (t < 128) { x += p; hist[t] = x; }
        __syncthreads();
    }
    if (t < 128) {
        int ex = hist[t] - deg_t;
        excl[t] = ex;
        cur[t] = ex;
        if (t < nn) {
            rowptr[n0 + t] = base + ex;
            int sg = sgp[t];
            int lt = sg >> 10, eq = sg & 1023;
            float ss = (float)(deg_t - eq - 2 * lt);
            ssinv[n0 + t] = (deg_t > 0) ? ss / (float)deg_t : 0.f;
        }
    }
    __syncthreads();
    for (int off = 0; off < cnt; off += BCAP) {
        int bs = min(BCAP, cnt - off);
        if (!single) {
            for (int i = t; i < bs; i += 256) st[i] = bucketed[b * CAPB + off + i];
            __syncthreads();
        }
        for (int i = t; i < bs; i += 256) {
            unsigned w = st[i];
            int dl = (int)(w >> 16) - n0;
            unsigned short sval = (unsigned short)(w & 0xffffu);
            int p = atomicAdd(&cur[dl], 1);
            csr[base + p] = sval;
            int r = p - excl[dl];
            if (r < 64) pcsr[((size_t)(n0 + dl) << 6) + r] = sval;
        }
        if (!single) __syncthreads();
    }
}

// conv_in: x [N,1] fp32 -> packed fp16 [N,32] dwords
__global__ void k_in(int N, const float* __restrict__ x0,
                     const int* __restrict__ rowptr, const unsigned short* __restrict__ csr,
                     const float* __restrict__ ssinv,
                     const float* __restrict__ W_in, const float* __restrict__ b_in,
                     unsigned* __restrict__ xoutP) {
    int wid = blockIdx.x * (blockDim.x >> 6) + (threadIdx.x >> 6);
    int lane = threadIdx.x & 63;
    if (wid >= N) return;
    int beg = rowptr[wid], end = rowptr[wid + 1];
    int deg = end - beg;
    float s = 0.f;
    for (int e = beg + lane; e < end; e += 64) s += x0[csr[e]];
    for (int m = 32; m >= 1; m >>= 1) s += __shfl_xor(s, m, 64);
    float invd = 1.f / (float)max(deg, 1);
    float mean = s * invd;
    float xi = x0[wid];
    float w1 = W_in[lane], w2 = W_in[64 + lane], w3 = W_in[128 + lane];
    float y = xi * (w1 - w2) + mean * w2 + ssinv[wid] * w3 + b_in[lane];
    if (deg == 0) y = 0.f;
    float ylo = __shfl(y, (2 * lane) & 63, 64);
    float yhi = __shfl(y, (2 * lane + 1) & 63, 64);
    unsigned pkd = packh(ylo, yhi);
    if (lane < 32) xoutP[(size_t)wid * 32 + lane] = pkd;
}

// rare exact-csr gather (deg>64), f32 accumulate, reduced into a[8]
static __device__ __forceinline__ void slow_gather(
        const uint4* __restrict__ xin16, const unsigned short* __restrict__ csr,
        int beg, int end, int N, int lane, int sub, int lq, float* a) {
#pragma unroll
    for (int j = 0; j < 8; ++j) a[j] = 0.f;
    for (int tb = beg; tb < end; tb += 64) {
        int cnt = min(64, end - tb);
        int sv = (lane < cnt) ? (int)csr[tb + lane] : N;
        int ng = (cnt + 7) >> 3;
        for (int g = 0; g < ng; ++g) {
            int si = __shfl(sv, (g << 3) + sub, 64);
            uint4 d = xin16[(size_t)si * 8 + lq];
            a[0] += h_lo(d.x); a[1] += h_hi(d.x);
            a[2] += h_lo(d.y); a[3] += h_hi(d.y);
            a[4] += h_lo(d.z); a[5] += h_hi(d.z);
            a[6] += h_lo(d.w); a[7] += h_hi(d.w);
        }
    }
#pragma unroll
    for (int m = 8; m <= 32; m <<= 1) {
#pragma unroll
        for (int j = 0; j < 8; ++j) a[j] += __shfl_xor(a[j], m, 64);
    }
}

// Fused layer: branch-free paired gather (fp16 pk accumulate) -> LDS A=[x_i|M] -> MFMA -> epilogue.
// Block = 256 threads = 16 nodes; wave w owns output h-tile [16w,16w+16).
template <bool RES>
__global__ __launch_bounds__(256) void k_layer(
        int N, const unsigned* __restrict__ xinP,
        const unsigned* __restrict__ xresP, unsigned* __restrict__ xoutP,
        const int* __restrict__ rowptr, const unsigned short* __restrict__ csr,
        const unsigned short* __restrict__ pcsr,
        const float* __restrict__ ssinv,
        const unsigned short* __restrict__ WThl,   // [64 h][128 k] fp16
        const float* __restrict__ W3, const float* __restrict__ bias) {
    __shared__ unsigned Ald[16 * 64];   // 16 nodes x 64 dwords (128 f16), XOR-swizzled 16B groups
    __shared__ float Cld[16 * 64];
    __shared__ int sdeg[16];
    __shared__ float sss[16];

    int t = threadIdx.x;
    int lane = t & 63;
    int wv = t >> 6;
    int n0 = blockIdx.x << 4;
    int kg = lane >> 4;

    // B-fragments for this wave's h-tile (16 VGPRs, whole kernel)
    int cb = (wv << 4) + (lane & 15);
    const uint4* wp = (const uint4*)WThl;
    uint4 b0 = wp[cb * 16 + kg + 0];
    uint4 b1 = wp[cb * 16 + kg + 4];
    uint4 b2 = wp[cb * 16 + kg + 8];
    uint4 b3 = wp[cb * 16 + kg + 12];

    const uint4* xin16 = (const uint4*)xinP;
    int sub = lane >> 3;     // which of 8 rows in a group this lane serves
    int lq = lane & 7;       // 16B slice within the 128B row
    int ndb = wv << 2;

    // preload padded-csr rows for all 4 nodes (rows exist through NB*128; sentinel-filled)
    int svp[4];
#pragma unroll
    for (int q = 0; q < 4; ++q)
        svp[q] = (int)pcsr[((size_t)(n0 + ndb + q) << 6) + lane];

    // ---- gather phase: 2 nodes jointly per step (16 loads in flight) ----
#pragma unroll
    for (int qp = 0; qp < 2; ++qp) {
        int ndA = ndb + (qp << 1);
        int ndB = ndA + 1;
        int nodeA = n0 + ndA, nodeB = n0 + ndB;
        int ncA = min(nodeA, N - 1), ncB = min(nodeB, N - 1);
        int begA = __builtin_amdgcn_readfirstlane(rowptr[ncA]);
        int endA = __builtin_amdgcn_readfirstlane(rowptr[ncA + 1]);
        int begB = __builtin_amdgcn_readfirstlane(rowptr[ncB]);
        int endB = __builtin_amdgcn_readfirstlane(rowptr[ncB + 1]);
        int degA = (nodeA < N) ? (endA - begA) : 0;
        int degB = (nodeB < N) ? (endB - begB) : 0;
        float ssvA = ssinv[ncA];
        float ssvB = ssinv[ncB];
        uint4 xiA = make_uint4(0u, 0u, 0u, 0u), xiB = make_uint4(0u, 0u, 0u, 0u);
        if (lane < 8) {
            xiA = xin16[(size_t)ncA * 8 + lane];
            xiB = xin16[(size_t)ncB * 8 + lane];
        }
        uint4 mvA, mvB;
        if (max(degA, degB) <= 64) {
            // branch-free fast pair: 16 shfl, 16 unguarded uint4 loads, 2 fp16 trees
            int svA = svp[qp << 1], svB = svp[(qp << 1) + 1];
            int sA0 = __shfl(svA, sub, 64),      sB0 = __shfl(svB, sub, 64);
            int sA1 = __shfl(svA, 8 + sub, 64),  sB1 = __shfl(svB, 8 + sub, 64);
            int sA2 = __shfl(svA, 16 + sub, 64), sB2 = __shfl(svB, 16 + sub, 64);
            int sA3 = __shfl(svA, 24 + sub, 64), sB3 = __shfl(svB, 24 + sub, 64);
            int sA4 = __shfl(svA, 32 + sub, 64), sB4 = __shfl(svB, 32 + sub, 64);
            int sA5 = __shfl(svA, 40 + sub, 64), sB5 = __shfl(svB, 40 + sub, 64);
            int sA6 = __shfl(svA, 48 + sub, 64), sB6 = __shfl(svB, 48 + sub, 64);
            int sA7 = __shfl(svA, 56 + sub, 64), sB7 = __shfl(svB, 56 + sub, 64);
            uint4 dA0 = xin16[(size_t)sA0 * 8 + lq];
            uint4 dA1 = xin16[(size_t)sA1 * 8 + lq];
            uint4 dA2 = xin16[(size_t)sA2 * 8 + lq];
            uint4 dA3 = xin16[(size_t)sA3 * 8 + lq];
            uint4 dA4 = xin16[(size_t)sA4 * 8 + lq];
            uint4 dA5 = xin16[(size_t)sA5 * 8 + lq];
            uint4 dA6 = xin16[(size_t)sA6 * 8 + lq];
            uint4 dA7 = xin16[(size_t)sA7 * 8 + lq];
            uint4 dB0 = xin16[(size_t)sB0 * 8 + lq];
            uint4 dB1 = xin16[(size_t)sB1 * 8 + lq];
            uint4 dB2 = xin16[(size_t)sB2 * 8 + lq];
            uint4 dB3 = xin16[(size_t)sB3 * 8 + lq];
            uint4 dB4 = xin16[(size_t)sB4 * 8 + lq];
            uint4 dB5 = xin16[(size_t)sB5 * 8 + lq];
            uint4 dB6 = xin16[(size_t)sB6 * 8 + lq];
            uint4 dB7 = xin16[(size_t)sB7 * 8 + lq];
            unsigned uA0 = h2u(hsum8(dA0.x, dA1.x, dA2.x, dA3.x, dA4.x, dA5.x, dA6.x, dA7.x));
            unsigned uA1 = h2u(hsum8(dA0.y, dA1.y, dA2.y, dA3.y, dA4.y, dA5.y, dA6.y, dA7.y));
            unsigned uA2 = h2u(hsum8(dA0.z, dA1.z, dA2.z, dA3.z, dA4.z, dA5.z, dA6.z, dA7.z));
            unsigned uA3 = h2u(hsum8(dA0.w, dA1.w, dA2.w, dA3.w, dA4.w, dA5.w, dA6.w, dA7.w));
            unsigned uB0 = h2u(hsum8(dB0.x, dB1.x, dB2.x, dB3.x, dB4.x, dB5.x, dB6.x, dB7.x));
            unsigned uB1 = h2u(hsum8(dB0.y, dB1.y, dB2.y, dB3.y, dB4.y, dB5.y, dB6.y, dB7.y));
            unsigned uB2 = h2u(hsum8(dB0.z, dB1.z, dB2.z, dB3.z, dB4.z, dB5.z, dB6.z, dB7.z));
            unsigned uB3 = h2u(hsum8(dB0.w, dB1.w, dB2.w, dB3.w, dB4.w, dB5.w, dB6.w, dB7.w));
#pragma unroll
            for (int m = 8; m <= 32; m <<= 1) {
                uA0 = h2u(__hadd2(uh2(uA0), uh2((unsigned)__shfl_xor((int)uA0, m, 64))));
                uA1 = h2u(__hadd2(uh2(uA1), uh2((unsigned)__shfl_xor((int)uA1, m, 64))));
                uA2 = h2u(__hadd2(uh2(uA2), uh2((unsigned)__shfl_xor((int)uA2, m, 64))));
                uA3 = h2u(__hadd2(uh2(uA3), uh2((unsigned)__shfl_xor((int)uA3, m, 64))));
                uB0 = h2u(__hadd2(uh2(uB0), uh2((unsigned)__shfl_xor((int)uB0, m, 64))));
                uB1 = h2u(__hadd2(uh2(uB1), uh2((unsigned)__shfl_xor((int)uB1, m, 64))));
                uB2 = h2u(__hadd2(uh2(uB2), uh2((unsigned)__shfl_xor((int)uB2, m, 64))));
                uB3 = h2u(__hadd2(uh2(uB3), uh2((unsigned)__shfl_xor((int)uB3, m, 64))));
            }
            float idA = 1.f / (float)max(degA, 1);
            float idB = 1.f / (float)max(degB, 1);
            mvA.x = packh(__half2float(__low2half(uh2(uA0))) * idA, __half2float(__high2half(uh2(uA0))) * idA);
            mvA.y = packh(__half2float(__low2half(uh2(uA1))) * idA, __half2float(__high2half(uh2(uA1))) * idA);
            mvA.z = packh(__half2float(__low2half(uh2(uA2))) * idA, __half2float(__high2half(uh2(uA2))) * idA);
            mvA.w = packh(__half2float(__low2half(uh2(uA3))) * idA, __half2float(__high2half(uh2(uA3))) * idA);
            mvB.x = packh(__half2float(__low2half(uh2(uB0))) * idB, __half2float(__high2half(uh2(uB0))) * idB);
            mvB.y = packh(__half2float(__low2half(uh2(uB1))) * idB, __half2float(__high2half(uh2(uB1))) * idB);
            mvB.z = packh(__half2float(__low2half(uh2(uB2))) * idB, __half2float(__high2half(uh2(uB2))) * idB);
            mvB.w = packh(__half2float(__low2half(uh2(uB3))) * idB, __half2float(__high2half(uh2(uB3))) * idB);
        } else {
            float aA[8], aB[8];
            slow_gather(xin16, csr, begA, endA, N, lane, sub, lq, aA);
            slow_gather(xin16, csr, begB, endB, N, lane, sub, lq, aB);
            float idA = 1.f / (float)max(degA, 1);
            float idB = 1.f / (float)max(degB, 1);
            mvA.x = packh(aA[0] * idA, aA[1] * idA);
            mvA.y = packh(aA[2] * idA, aA[3] * idA);
            mvA.z = packh(aA[4] * idA, aA[5] * idA);
            mvA.w = packh(aA[6] * idA, aA[7] * idA);
            mvB.x = packh(aB[0] * idB, aB[1] * idB);
            mvB.y = packh(aB[2] * idB, aB[3] * idB);
            mvB.z = packh(aB[4] * idB, aB[5] * idB);
            mvB.w = packh(aB[6] * idB, aB[7] * idB);
        }
        if (lane < 8) {
            int gxA = lane ^ (ndA & 7), gmA = (8 + lane) ^ (ndA & 7);
            int gxB = lane ^ (ndB & 7), gmB = (8 + lane) ^ (ndB & 7);
            ((uint4*)Ald)[ndA * 16 + gxA] = xiA;
            ((uint4*)Ald)[ndA * 16 + gmA] = mvA;
            ((uint4*)Ald)[ndB * 16 + gxB] = xiB;
            ((uint4*)Ald)[ndB * 16 + gmB] = mvB;
        }
        if (lane == 0) {
            sdeg[ndA] = degA; sss[ndA] = ssvA;
            sdeg[ndB] = degB; sss[ndB] = ssvB;
        }
    }
    __syncthreads();

    // ---- MFMA: C[16 nodes][16 h] = A[16][128] @ B[128][16] ----
    int r = lane & 15;
    const uint4* ap = (const uint4*)Ald;
    int rx = (r & 7);
    uint4 fa0 = ap[r * 16 + ((0 + kg) ^ rx)];
    uint4 fa1 = ap[r * 16 + ((4 + kg) ^ rx)];
    uint4 fa2 = ap[r * 16 + ((8 + kg) ^ rx)];
    uint4 fa3 = ap[r * 16 + ((12 + kg) ^ rx)];
    f32x4 acc = {0.f, 0.f, 0.f, 0.f};
    acc = __builtin_amdgcn_mfma_f32_16x16x32_f16(u4h(fa0), u4h(b0), acc, 0, 0, 0);
    acc = __builtin_amdgcn_mfma_f32_16x16x32_f16(u4h(fa1), u4h(b1), acc, 0, 0, 0);
    acc = __builtin_amdgcn_mfma_f32_16x16x32_f16(u4h(fa2), u4h(b2), acc, 0, 0, 0);
    acc = __builtin_amdgcn_mfma_f32_16x16x32_f16(u4h(fa3), u4h(b3), acc, 0, 0, 0);
#pragma unroll
    for (int reg = 0; reg < 4; ++reg)
        Cld[(kg * 4 + reg) * 64 + (wv << 4) + r] = acc[reg];
    __syncthreads();

    // ---- epilogue: thread t -> node t>>4, dword cols (t&15) and (t&15)+16 ----
    int nd = t >> 4;
    int node = n0 + nd;
    if (node < N) {
        int dg = sdeg[nd];
        float ss = sss[nd];
#pragma unroll
        for (int jj = 0; jj < 2; ++jj) {
            int j = (t & 15) + jj * 16;
            float y0 = Cld[nd * 64 + 2 * j];
            float y1 = Cld[nd * 64 + 2 * j + 1];
            float2 w3 = ((const float2*)W3)[j];
            float2 bb = ((const float2*)bias)[j];
            y0 += ss * w3.x + bb.x;
            y1 += ss * w3.y + bb.y;
            if (dg == 0) { y0 = 0.f; y1 = 0.f; }
            if (RES) {
                unsigned rw = xresP[(size_t)node * 32 + j];
                y0 += h_lo(rw);
                y1 += h_hi(rw);
            }
            y0 = (y0 > 0.f) ? y0 : NEG_SLOPE * y0;
            y1 = (y1 > 0.f) ? y1 : NEG_SLOPE * y1;
            xoutP[(size_t)node * 32 + j] = packh(y0, y1);
        }
    }
}

// t[i] = dot(x'[i], W_out[64:128])
__global__ void k_t(int N, const unsigned* __restrict__ xAP, const float* __restrict__ Wt,
                    float* __restrict__ t) {
    int wid = blockIdx.x * (blockDim.x >> 6) + (threadIdx.x >> 6);
    int lane = threadIdx.x & 63;
    if (wid >= N) return;
    float p = 0.f;
    if (lane < 32) {
        unsigned d = xAP[(size_t)wid * 32 + lane];
        float2 wt = ((const float2*)Wt)[lane];
        p = h_lo(d) * wt.x + h_hi(d) * wt.y;
    }
    for (int m = 32; m >= 1; m >>= 1) p += __shfl_xor(p, m, 64);
    if (lane == 0) t[wid] = p;
}

// conv_out + residual x
__global__ void k_out(int N, const unsigned* __restrict__ xAP, const float* __restrict__ x0,
                      const int* __restrict__ rowptr, const unsigned short* __restrict__ csr,
                      const float* __restrict__ ssinv, const float* __restrict__ t,
                      const float* __restrict__ W_out, const float* __restrict__ b_out,
                      float* __restrict__ out) {
    int wid = blockIdx.x * (blockDim.x >> 6) + (threadIdx.x >> 6);
    int lane = threadIdx.x & 63;
    if (wid >= N) return;
    int beg = rowptr[wid], end = rowptr[wid + 1];
    int deg = end - beg;
    float s = 0.f;
    for (int e = beg + lane; e < end; e += 64) s += t[csr[e]];
    unsigned xw = xAP[(size_t)wid * 32 + (lane >> 1)];
    float xf = (lane & 1) ? h_hi(xw) : h_lo(xw);
    float p = xf * (W_out[lane] - W_out[64 + lane]);
    for (int m = 32; m >= 1; m >>= 1) {
        s += __shfl_xor(s, m, 64);
        p += __shfl_xor(p, m, 64);
    }
    float invd = 1.f / (float)max(deg, 1);
    float y = p + s * invd + ssinv[wid] * W_out[128] + b_out[0];
    if (deg == 0) y = 0.f;
    if (lane == 0) out[wid] = y + x0[wid];
}

static inline size_t align16(size_t x) { return (x + 15) & ~(size_t)15; }

extern "C" void kernel_launch(void* const* d_in, const int* in_sizes, int n_in,
                              void* d_out, int out_size, void* d_ws, size_t ws_size,
                              hipStream_t stream) {
    const float* x0    = (const float*)d_in[0];
    const int*   ei    = (const int*)d_in[1];
    const float* W_in  = (const float*)d_in[2];
    const float* b_in  = (const float*)d_in[3];
    const float* W_mid = (const float*)d_in[4];
    const float* b_mid = (const float*)d_in[5];
    const float* W_out = (const float*)d_in[6];
    const float* b_out = (const float*)d_in[7];
    float* out = (float*)d_out;

    const int N = in_sizes[0];
    const int E = in_sizes[1] / 2;
    const int L = in_sizes[4] / (129 * 64);
    const int NB = (N + 127) >> 7;
    const int* src = ei;
    const int* dst = ei + E;

    char* p = (char*)d_ws;
    unsigned short* WTh = (unsigned short*)p; p += align16((size_t)L * 64 * 128 * 2);
    unsigned* xAP = (unsigned*)p; p += align16((size_t)(N + 1) * 32 * 4);
    unsigned* xBP = (unsigned*)p; p += align16((size_t)(N + 1) * 32 * 4);
    unsigned* bucketed = (unsigned*)p; p += align16((size_t)NB * CAPB * 4);
    unsigned short* csr = (unsigned short*)p; p += align16((size_t)E * 2);
    unsigned short* pcsr = (unsigned short*)p; p += align16((size_t)NB * 8192 * 2);
    int* gcur          = (int*)p; p += align16((size_t)(NB + 1) * 4);
    int* gstart        = (int*)p; p += align16((size_t)(NB + 1) * 4);
    int* rowptr        = (int*)p; p += align16((size_t)(N + 1) * 4);
    float* ssinv       = (float*)p; p += align16((size_t)N * 4);
    float* t           = (float*)p; p += align16((size_t)N * 4);

    const int nb_w4 = (N + 3) / 4;
    const int nb_bkt = (E + 2047) / 2048;
    const int ptotal = L * 64 * 128;
    const int nb_lay = (N + 15) / 16;

    k_setup<<<(ptotal + 255) / 256, 256, 0, stream>>>(ptotal, W_mid, WTh, NB, gcur, N, xAP, xBP);
    k_bucket<<<nb_bkt, 256, 0, stream>>>(E, src, dst, gcur, bucketed, NB);
    k_bktscan<<<1, 512, 0, stream>>>(NB, N, gcur, gstart, rowptr);
    k_csr<<<NB, 256, 0, stream>>>(N, bucketed, gcur, gstart, csr, pcsr, rowptr, ssinv);

    k_in<<<nb_w4, 256, 0, stream>>>(N, x0, rowptr, csr, ssinv, W_in, b_in, xAP);

    for (int l = 0; l < L / 2; ++l) {
        const unsigned short* Wa = WTh + (size_t)(2 * l) * 64 * 128;
        const unsigned short* Wb = WTh + (size_t)(2 * l + 1) * 64 * 128;
        const float* W3a = W_mid + (size_t)(2 * l) * 129 * 64 + 128 * 64;
        const float* W3b = W_mid + (size_t)(2 * l + 1) * 129 * 64 + 128 * 64;

        // x1 = leaky(conv(x2)) : xAP -> xBP
        k_layer<false><<<nb_lay, 256, 0, stream>>>(
            N, xAP, nullptr, xBP, rowptr, csr, pcsr, ssinv,
            Wa, W3a, b_mid + (size_t)(2 * l) * HDIM);
        // x2 = leaky(conv(x1) + x2) : xBP (+xAP) -> xAP
        k_layer<true><<<nb_lay, 256, 0, stream>>>(
            N, xBP, xAP, xAP, rowptr, csr, pcsr, ssinv,
            Wb, W3b, b_mid + (size_t)(2 * l + 1) * HDIM);
    }

    k_t<<<nb_w4, 256, 0, stream>>>(N, xAP, W_out + 64, t);
    k_out<<<nb_w4, 256, 0, stream>>>(N, xAP, x0, rowptr, csr, ssinv, t,
                                     W_out, b_out, out);
}

// Round 9
// 254.719 us; speedup vs baseline: 2.4929x; 1.0614x over previous
//
#include <hip/hip_runtime.h>
#include <hip/hip_fp16.h>

#define HDIM 64
#define NEG_SLOPE 0.01f
#define CAPB 8192      // bucketed[] region per 128-node bucket
#define BCAP 6144      // LDS staging capacity in k_csr

typedef _Float16 half8 __attribute__((ext_vector_type(8)));
typedef float f32x4 __attribute__((ext_vector_type(4)));

static __device__ __forceinline__ float h_lo(unsigned d) {
    return __half2float(__ushort_as_half((unsigned short)(d & 0xffffu)));
}
static __device__ __forceinline__ float h_hi(unsigned d) {
    return __half2float(__ushort_as_half((unsigned short)(d >> 16)));
}
static __device__ __forceinline__ unsigned packh(float a, float b) {
    unsigned short ra = __half_as_ushort(__float2half(a));
    unsigned short rb = __half_as_ushort(__float2half(b));
    return ((unsigned)rb << 16) | (unsigned)ra;
}
static __device__ __forceinline__ half8 u4h(uint4 v) {
    union { uint4 u; half8 h; } x; x.u = v; return x.h;
}
static __device__ __forceinline__ __half2 uh2(unsigned u) {
    union { unsigned u; __half2 h; } x; x.u = u; return x.h;
}

// merged setup: WTh prep + gcur init + sentinel feature rows
__global__ void k_setup(int ptotal, const float* __restrict__ W_mid,
                        unsigned short* __restrict__ WTh,
                        int NB, int* gcur, int N, unsigned* xAP, unsigned* xBP) {
    int i = blockIdx.x * blockDim.x + threadIdx.x;
    if (i < ptotal) {
        int l = i >> 13;
        int rem = i & 8191;
        int h = rem >> 7;
        int k = rem & 127;
        const float* W = W_mid + (size_t)l * 129 * 64;
        float v = W[k * 64 + h] - ((k < 64) ? W[(64 + k) * 64 + h] : 0.f);
        WTh[i] = __half_as_ushort(__float2half(v));
    }
    if (i < NB) gcur[i] = i * CAPB;
    if (i < 32) xAP[(size_t)N * 32 + i] = 0u;
    else if (i < 64) xBP[(size_t)N * 32 + (i - 32)] = 0u;
}

// Phase 1: bucket edges by dst>>7; 1024 threads/block, 2 edges/thread (short chains, 32 waves/CU).
__global__ __launch_bounds__(1024) void k_bucket(
        int E, const int* __restrict__ src, const int* __restrict__ dst,
        int* gcur, unsigned* __restrict__ bucketed, int NB) {
    __shared__ int lh[512];
    __shared__ int lbase[512];
    int t = threadIdx.x;
    int e0 = blockIdx.x * 2048;
    if (t < 512) lh[t] = 0;
    __syncthreads();
    int e1 = e0 + t, e2 = e0 + 1024 + t;
    int d1 = (e1 < E) ? dst[e1] : -1;
    int d2 = (e2 < E) ? dst[e2] : -1;
    if (d1 >= 0) atomicAdd(&lh[((unsigned)d1) >> 7], 1);
    if (d2 >= 0) atomicAdd(&lh[((unsigned)d2) >> 7], 1);
    __syncthreads();
    if (t < NB) {
        int c = lh[t];
        lbase[t] = (c > 0) ? atomicAdd(&gcur[t], c) : 0;
        lh[t] = 0;
    }
    __syncthreads();
    int s1 = (e1 < E) ? src[e1] : 0;
    int s2 = (e2 < E) ? src[e2] : 0;
    if (d1 >= 0) {
        int b = ((unsigned)d1) >> 7;
        int r = atomicAdd(&lh[b], 1);
        int pos = lbase[b] + r;
        if (pos < (b + 1) * CAPB)
            bucketed[pos] = ((unsigned)d1 << 16) | (unsigned)s1;
    }
    if (d2 >= 0) {
        int b = ((unsigned)d2) >> 7;
        int r = atomicAdd(&lh[b], 1);
        int pos = lbase[b] + r;
        if (pos < (b + 1) * CAPB)
            bucketed[pos] = ((unsigned)d2 << 16) | (unsigned)s2;
    }
}

// Exclusive scan of bucket counts -> gstart; rowptr[N].
__global__ void k_bktscan(int NB, int N, const int* __restrict__ gcur,
                          int* gstart, int* rowptr) {
    __shared__ int sd[512];
    int t = threadIdx.x;
    int c = (t < NB) ? min(gcur[t] - t * CAPB, CAPB) : 0;
    sd[t] = c;
    __syncthreads();
    int x = c;
    for (int s = 1; s < 512; s <<= 1) {
        int p = (t >= s) ? sd[t - s] : 0;
        __syncthreads();
        x += p;
        sd[t] = x;
        __syncthreads();
    }
    if (t < NB) gstart[t] = x - c;
    if (t == NB - 1) {
        gstart[NB] = x;
        rowptr[N] = x;
    }
}

// Phase 2: per bucket, LDS hist+scan -> rowptr/ssinv, exact csr AND padded pcsr.
__global__ void k_csr(int N, const unsigned* __restrict__ bucketed, const int* __restrict__ gcur,
                      const int* __restrict__ gstart, unsigned short* __restrict__ csr,
                      unsigned short* __restrict__ pcsr,
                      int* __restrict__ rowptr, float* __restrict__ ssinv) {
    __shared__ unsigned st[BCAP];
    __shared__ int hist[128], cur[128], excl[128], sgp[128];
    int b = blockIdx.x, t = threadIdx.x;
    int n0 = b << 7;
    int nn = min(128, N - n0);
    int cnt = min(gcur[b] - b * CAPB, CAPB);
    int base = gstart[b];
    if (t < 128) { hist[t] = 0; sgp[t] = 0; }
    unsigned sent = ((unsigned)N << 16) | (unsigned)N;
    unsigned* pb32 = (unsigned*)(pcsr + ((size_t)b << 13));
    for (int i = t; i < 4096; i += 256) pb32[i] = sent;
    __syncthreads();
    bool single = (cnt <= BCAP);
    for (int off = 0; off < cnt; off += BCAP) {
        int bs = min(BCAP, cnt - off);
        for (int i = t; i < bs; i += 256) {
            unsigned w = bucketed[b * CAPB + off + i];
            if (single) st[i] = w;
            int d = (int)(w >> 16);
            int s = (int)(w & 0xffffu);
            int dl = d - n0;
            atomicAdd(&hist[dl], 1);
            atomicAdd(&sgp[dl], ((s < d) ? 1024 : 0) + ((s == d) ? 1 : 0));
        }
    }
    __syncthreads();
    int deg_t = (t < 128) ? hist[t] : 0;
    int x = deg_t;
    for (int s = 1; s < 128; s <<= 1) {
        int p = (t < 128 && t >= s) ? hist[t - s] : 0;
        __syncthreads();
        if (t < 128) { x += p; hist[t] = x; }
        __syncthreads();
    }
    if (t < 128) {
        int ex = hist[t] - deg_t;
        excl[t] = ex;
        cur[t] = ex;
        if (t < nn) {
            rowptr[n0 + t] = base + ex;
            int sg = sgp[t];
            int lt = sg >> 10, eq = sg & 1023;
            float ss = (float)(deg_t - eq - 2 * lt);
            ssinv[n0 + t] = (deg_t > 0) ? ss / (float)deg_t : 0.f;
        }
    }
    __syncthreads();
    for (int off = 0; off < cnt; off += BCAP) {
        int bs = min(BCAP, cnt - off);
        if (!single) {
            for (int i = t; i < bs; i += 256) st[i] = bucketed[b * CAPB + off + i];
            __syncthreads();
        }
        for (int i = t; i < bs; i += 256) {
            unsigned w = st[i];
            int dl = (int)(w >> 16) - n0;
            unsigned short sval = (unsigned short)(w & 0xffffu);
            int p = atomicAdd(&cur[dl], 1);
            csr[base + p] = sval;
            int r = p - excl[dl];
            if (r < 64) pcsr[((size_t)(n0 + dl) << 6) + r] = sval;
        }
        if (!single) __syncthreads();
    }
}

// conv_in: x [N,1] fp32 -> packed fp16 [N,32] dwords
__global__ void k_in(int N, const float* __restrict__ x0,
                     const int* __restrict__ rowptr, const unsigned short* __restrict__ csr,
                     const float* __restrict__ ssinv,
                     const float* __restrict__ W_in, const float* __restrict__ b_in,
                     unsigned* __restrict__ xoutP) {
    int wid = blockIdx.x * (blockDim.x >> 6) + (threadIdx.x >> 6);
    int lane = threadIdx.x & 63;
    if (wid >= N) return;
    int beg = rowptr[wid], end = rowptr[wid + 1];
    int deg = end - beg;
    float s = 0.f;
    for (int e = beg + lane; e < end; e += 64) s += x0[csr[e]];
    for (int m = 32; m >= 1; m >>= 1) s += __shfl_xor(s, m, 64);
    float invd = 1.f / (float)max(deg, 1);
    float mean = s * invd;
    float xi = x0[wid];
    float w1 = W_in[lane], w2 = W_in[64 + lane], w3 = W_in[128 + lane];
    float y = xi * (w1 - w2) + mean * w2 + ssinv[wid] * w3 + b_in[lane];
    if (deg == 0) y = 0.f;
    float ylo = __shfl(y, (2 * lane) & 63, 64);
    float yhi = __shfl(y, (2 * lane + 1) & 63, 64);
    unsigned pkd = packh(ylo, yhi);
    if (lane < 32) xoutP[(size_t)wid * 32 + lane] = pkd;
}

// one 32-slot chunk: 4 shfl + 4 unguarded uint4 loads, fp16 packed accumulate
static __device__ __forceinline__ void chunk_acc(
        const uint4* __restrict__ xin16, int sv, int base, int sub, int lq,
        __half2& c0, __half2& c1, __half2& c2, __half2& c3) {
    int s0 = __shfl(sv, base + sub, 64);
    int s1 = __shfl(sv, base + 8 + sub, 64);
    int s2 = __shfl(sv, base + 16 + sub, 64);
    int s3 = __shfl(sv, base + 24 + sub, 64);
    uint4 d0 = xin16[(size_t)s0 * 8 + lq];
    uint4 d1 = xin16[(size_t)s1 * 8 + lq];
    uint4 d2 = xin16[(size_t)s2 * 8 + lq];
    uint4 d3 = xin16[(size_t)s3 * 8 + lq];
    c0 = __hadd2(c0, __hadd2(__hadd2(uh2(d0.x), uh2(d1.x)), __hadd2(uh2(d2.x), uh2(d3.x))));
    c1 = __hadd2(c1, __hadd2(__hadd2(uh2(d0.y), uh2(d1.y)), __hadd2(uh2(d2.y), uh2(d3.y))));
    c2 = __hadd2(c2, __hadd2(__hadd2(uh2(d0.z), uh2(d1.z)), __hadd2(uh2(d2.z), uh2(d3.z))));
    c3 = __hadd2(c3, __hadd2(__hadd2(uh2(d0.w), uh2(d1.w)), __hadd2(uh2(d2.w), uh2(d3.w))));
}

// rare exact-csr gather (deg>64), f32 accumulate, reduced into a[8]
static __device__ __forceinline__ void slow_gather(
        const uint4* __restrict__ xin16, const unsigned short* __restrict__ csr,
        int beg, int end, int N, int lane, int sub, int lq, float* a) {
#pragma unroll
    for (int j = 0; j < 8; ++j) a[j] = 0.f;
    for (int tb = beg; tb < end; tb += 64) {
        int cnt = min(64, end - tb);
        int sv = (lane < cnt) ? (int)csr[tb + lane] : N;
        int ng = (cnt + 7) >> 3;
        for (int g = 0; g < ng; ++g) {
            int si = __shfl(sv, (g << 3) + sub, 64);
            uint4 d = xin16[(size_t)si * 8 + lq];
            a[0] += h_lo(d.x); a[1] += h_hi(d.x);
            a[2] += h_lo(d.y); a[3] += h_hi(d.y);
            a[4] += h_lo(d.z); a[5] += h_hi(d.z);
            a[6] += h_lo(d.w); a[7] += h_hi(d.w);
        }
    }
#pragma unroll
    for (int m = 8; m <= 32; m <<= 1) {
#pragma unroll
        for (int j = 0; j < 8; ++j) a[j] += __shfl_xor(a[j], m, 64);
    }
}

// Fused layer: chunk-adaptive paired gather -> LDS A=[x_i|M] -> MFMA -> epilogue (+ optional t).
// Block = 256 threads = 16 nodes; wave w owns output h-tile [16w,16w+16).
template <bool RES, bool TOUT>
__global__ __launch_bounds__(256) void k_layer(
        int N, const unsigned* __restrict__ xinP,
        const unsigned* __restrict__ xresP, unsigned* __restrict__ xoutP,
        const int* __restrict__ rowptr, const unsigned short* __restrict__ csr,
        const unsigned short* __restrict__ pcsr,
        const float* __restrict__ ssinv,
        const unsigned short* __restrict__ WThl,   // [64 h][128 k] fp16
        const float* __restrict__ W3, const float* __restrict__ bias,
        const float* __restrict__ Wt, float* __restrict__ tvec) {
    __shared__ unsigned Ald[16 * 64];   // 16 nodes x 64 dwords (128 f16), XOR-swizzled 16B groups
    __shared__ float Cld[16 * 64];
    __shared__ int sdeg[16];
    __shared__ float sss[16];

    int t = threadIdx.x;
    int lane = t & 63;
    int wv = t >> 6;
    int n0 = blockIdx.x << 4;
    int kg = lane >> 4;

    // B-fragments for this wave's h-tile (16 VGPRs, whole kernel)
    int cb = (wv << 4) + (lane & 15);
    const uint4* wp = (const uint4*)WThl;
    uint4 b0 = wp[cb * 16 + kg + 0];
    uint4 b1 = wp[cb * 16 + kg + 4];
    uint4 b2 = wp[cb * 16 + kg + 8];
    uint4 b3 = wp[cb * 16 + kg + 12];

    const uint4* xin16 = (const uint4*)xinP;
    int sub = lane >> 3;     // which of 8 rows in a group this lane serves
    int lq = lane & 7;       // 16B slice within the 128B row
    int ndb = wv << 2;

    // preload padded-csr rows for all 4 nodes (rows exist through NB*128; sentinel-filled)
    int svp[4];
#pragma unroll
    for (int q = 0; q < 4; ++q)
        svp[q] = (int)pcsr[((size_t)(n0 + ndb + q) << 6) + lane];

    // ---- gather phase: 2 nodes jointly per step; chunk-adaptive (skip all-sentinel chunks) ----
#pragma unroll
    for (int qp = 0; qp < 2; ++qp) {
        int ndA = ndb + (qp << 1);
        int ndB = ndA + 1;
        int nodeA = n0 + ndA, nodeB = n0 + ndB;
        int ncA = min(nodeA, N - 1), ncB = min(nodeB, N - 1);
        int begA = __builtin_amdgcn_readfirstlane(rowptr[ncA]);
        int endA = __builtin_amdgcn_readfirstlane(rowptr[ncA + 1]);
        int begB = __builtin_amdgcn_readfirstlane(rowptr[ncB]);
        int endB = __builtin_amdgcn_readfirstlane(rowptr[ncB + 1]);
        int degA = (nodeA < N) ? (endA - begA) : 0;
        int degB = (nodeB < N) ? (endB - begB) : 0;
        float ssvA = ssinv[ncA];
        float ssvB = ssinv[ncB];
        uint4 xiA = make_uint4(0u, 0u, 0u, 0u), xiB = make_uint4(0u, 0u, 0u, 0u);
        if (lane < 8) {
            xiA = xin16[(size_t)ncA * 8 + lane];
            xiB = xin16[(size_t)ncB * 8 + lane];
        }
        uint4 mvA, mvB;
        if (max(degA, degB) <= 64) {
            __half2 z = uh2(0u);
            __half2 cA0 = z, cA1 = z, cA2 = z, cA3 = z;
            __half2 cB0 = z, cB1 = z, cB2 = z, cB3 = z;
            int svA = svp[qp << 1], svB = svp[(qp << 1) + 1];
            // chunk 0 (slots 0..31) for both nodes: 8 loads in flight
            chunk_acc(xin16, svA, 0, sub, lq, cA0, cA1, cA2, cA3);
            chunk_acc(xin16, svB, 0, sub, lq, cB0, cB1, cB2, cB3);
            // tail chunks only when needed (wave-uniform)
            if (degA > 32) chunk_acc(xin16, svA, 32, sub, lq, cA0, cA1, cA2, cA3);
            if (degB > 32) chunk_acc(xin16, svB, 32, sub, lq, cB0, cB1, cB2, cB3);
            // cross-lane packed reduce over the 8 sub-groups
#pragma unroll
            for (int m = 8; m <= 32; m <<= 1) {
                cA0 = __hadd2(cA0, uh2((unsigned)__shfl_xor((int)*(unsigned*)&cA0, m, 64)));
                cA1 = __hadd2(cA1, uh2((unsigned)__shfl_xor((int)*(unsigned*)&cA1, m, 64)));
                cA2 = __hadd2(cA2, uh2((unsigned)__shfl_xor((int)*(unsigned*)&cA2, m, 64)));
                cA3 = __hadd2(cA3, uh2((unsigned)__shfl_xor((int)*(unsigned*)&cA3, m, 64)));
                cB0 = __hadd2(cB0, uh2((unsigned)__shfl_xor((int)*(unsigned*)&cB0, m, 64)));
                cB1 = __hadd2(cB1, uh2((unsigned)__shfl_xor((int)*(unsigned*)&cB1, m, 64)));
                cB2 = __hadd2(cB2, uh2((unsigned)__shfl_xor((int)*(unsigned*)&cB2, m, 64)));
                cB3 = __hadd2(cB3, uh2((unsigned)__shfl_xor((int)*(unsigned*)&cB3, m, 64)));
            }
            float idA = 1.f / (float)max(degA, 1);
            float idB = 1.f / (float)max(degB, 1);
            mvA.x = packh(__half2float(__low2half(cA0)) * idA, __half2float(__high2half(cA0)) * idA);
            mvA.y = packh(__half2float(__low2half(cA1)) * idA, __half2float(__high2half(cA1)) * idA);
            mvA.z = packh(__half2float(__low2half(cA2)) * idA, __half2float(__high2half(cA2)) * idA);
            mvA.w = packh(__half2float(__low2half(cA3)) * idA, __half2float(__high2half(cA3)) * idA);
            mvB.x = packh(__half2float(__low2half(cB0)) * idB, __half2float(__high2half(cB0)) * idB);
            mvB.y = packh(__half2float(__low2half(cB1)) * idB, __half2float(__high2half(cB1)) * idB);
            mvB.z = packh(__half2float(__low2half(cB2)) * idB, __half2float(__high2half(cB2)) * idB);
            mvB.w = packh(__half2float(__low2half(cB3)) * idB, __half2float(__high2half(cB3)) * idB);
        } else {
            float aA[8], aB[8];
            slow_gather(xin16, csr, begA, endA, N, lane, sub, lq, aA);
            slow_gather(xin16, csr, begB, endB, N, lane, sub, lq, aB);
            float idA = 1.f / (float)max(degA, 1);
            float idB = 1.f / (float)max(degB, 1);
            mvA.x = packh(aA[0] * idA, aA[1] * idA);
            mvA.y = packh(aA[2] * idA, aA[3] * idA);
            mvA.z = packh(aA[4] * idA, aA[5] * idA);
            mvA.w = packh(aA[6] * idA, aA[7] * idA);
            mvB.x = packh(aB[0] * idB, aB[1] * idB);
            mvB.y = packh(aB[2] * idB, aB[3] * idB);
            mvB.z = packh(aB[4] * idB, aB[5] * idB);
            mvB.w = packh(aB[6] * idB, aB[7] * idB);
        }
        if (lane < 8) {
            int gxA = lane ^ (ndA & 7), gmA = (8 + lane) ^ (ndA & 7);
            int gxB = lane ^ (ndB & 7), gmB = (8 + lane) ^ (ndB & 7);
            ((uint4*)Ald)[ndA * 16 + gxA] = xiA;
            ((uint4*)Ald)[ndA * 16 + gmA] = mvA;
            ((uint4*)Ald)[ndB * 16 + gxB] = xiB;
            ((uint4*)Ald)[ndB * 16 + gmB] = mvB;
        }
        if (lane == 0) {
            sdeg[ndA] = degA; sss[ndA] = ssvA;
            sdeg[ndB] = degB; sss[ndB] = ssvB;
        }
    }
    __syncthreads();

    // ---- MFMA: C[16 nodes][16 h] = A[16][128] @ B[128][16] ----
    int r = lane & 15;
    const uint4* ap = (const uint4*)Ald;
    int rx = (r & 7);
    uint4 fa0 = ap[r * 16 + ((0 + kg) ^ rx)];
    uint4 fa1 = ap[r * 16 + ((4 + kg) ^ rx)];
    uint4 fa2 = ap[r * 16 + ((8 + kg) ^ rx)];
    uint4 fa3 = ap[r * 16 + ((12 + kg) ^ rx)];
    f32x4 acc = {0.f, 0.f, 0.f, 0.f};
    acc = __builtin_amdgcn_mfma_f32_16x16x32_f16(u4h(fa0), u4h(b0), acc, 0, 0, 0);
    acc = __builtin_amdgcn_mfma_f32_16x16x32_f16(u4h(fa1), u4h(b1), acc, 0, 0, 0);
    acc = __builtin_amdgcn_mfma_f32_16x16x32_f16(u4h(fa2), u4h(b2), acc, 0, 0, 0);
    acc = __builtin_amdgcn_mfma_f32_16x16x32_f16(u4h(fa3), u4h(b3), acc, 0, 0, 0);
#pragma unroll
    for (int reg = 0; reg < 4; ++reg)
        Cld[(kg * 4 + reg) * 64 + (wv << 4) + r] = acc[reg];
    __syncthreads();

    // ---- epilogue: thread t -> node t>>4, dword cols (t&15) and (t&15)+16 ----
    int nd = t >> 4;
    int node = n0 + nd;
    if (node < N) {
        int dg = sdeg[nd];
        float ss = sss[nd];
        float tp = 0.f;
#pragma unroll
        for (int jj = 0; jj < 2; ++jj) {
            int j = (t & 15) + jj * 16;
            float y0 = Cld[nd * 64 + 2 * j];
            float y1 = Cld[nd * 64 + 2 * j + 1];
            float2 w3 = ((const float2*)W3)[j];
            float2 bb = ((const float2*)bias)[j];
            y0 += ss * w3.x + bb.x;
            y1 += ss * w3.y + bb.y;
            if (dg == 0) { y0 = 0.f; y1 = 0.f; }
            if (RES) {
                unsigned rw = xresP[(size_t)node * 32 + j];
                y0 += h_lo(rw);
                y1 += h_hi(rw);
            }
            y0 = (y0 > 0.f) ? y0 : NEG_SLOPE * y0;
            y1 = (y1 > 0.f) ? y1 : NEG_SLOPE * y1;
            if (TOUT) {
                float2 wt = ((const float2*)Wt)[j];
                tp += y0 * wt.x + y1 * wt.y;
            }
            xoutP[(size_t)node * 32 + j] = packh(y0, y1);
        }
        if (TOUT) {
            tp += __shfl_xor(tp, 1, 64);
            tp += __shfl_xor(tp, 2, 64);
            tp += __shfl_xor(tp, 4, 64);
            tp += __shfl_xor(tp, 8, 64);
            if ((t & 15) == 0) tvec[node] = tp;
        }
    }
}

// conv_out + residual x
__global__ void k_out(int N, const unsigned* __restrict__ xAP, const float* __restrict__ x0,
                      const int* __restrict__ rowptr, const unsigned short* __restrict__ csr,
                      const float* __restrict__ ssinv, const float* __restrict__ t,
                      const float* __restrict__ W_out, const float* __restrict__ b_out,
                      float* __restrict__ out) {
    int wid = blockIdx.x * (blockDim.x >> 6) + (threadIdx.x >> 6);
    int lane = threadIdx.x & 63;
    if (wid >= N) return;
    int beg = rowptr[wid], end = rowptr[wid + 1];
    int deg = end - beg;
    float s = 0.f;
    for (int e = beg + lane; e < end; e += 64) s += t[csr[e]];
    unsigned xw = xAP[(size_t)wid * 32 + (lane >> 1)];
    float xf = (lane & 1) ? h_hi(xw) : h_lo(xw);
    float p = xf * (W_out[lane] - W_out[64 + lane]);
    for (int m = 32; m >= 1; m >>= 1) {
        s += __shfl_xor(s, m, 64);
        p += __shfl_xor(p, m, 64);
    }
    float invd = 1.f / (float)max(deg, 1);
    float y = p + s * invd + ssinv[wid] * W_out[128] + b_out[0];
    if (deg == 0) y = 0.f;
    if (lane == 0) out[wid] = y + x0[wid];
}

static inline size_t align16(size_t x) { return (x + 15) & ~(size_t)15; }

extern "C" void kernel_launch(void* const* d_in, const int* in_sizes, int n_in,
                              void* d_out, int out_size, void* d_ws, size_t ws_size,
                              hipStream_t stream) {
    const float* x0    = (const float*)d_in[0];
    const int*   ei    = (const int*)d_in[1];
    const float* W_in  = (const float*)d_in[2];
    const float* b_in  = (const float*)d_in[3];
    const float* W_mid = (const float*)d_in[4];
    const float* b_mid = (const float*)d_in[5];
    const float* W_out = (const float*)d_in[6];
    const float* b_out = (const float*)d_in[7];
    float* out = (float*)d_out;

    const int N = in_sizes[0];
    const int E = in_sizes[1] / 2;
    const int L = in_sizes[4] / (129 * 64);
    const int NB = (N + 127) >> 7;
    const int* src = ei;
    const int* dst = ei + E;

    char* p = (char*)d_ws;
    unsigned short* WTh = (unsigned short*)p; p += align16((size_t)L * 64 * 128 * 2);
    unsigned* xAP = (unsigned*)p; p += align16((size_t)(N + 1) * 32 * 4);
    unsigned* xBP = (unsigned*)p; p += align16((size_t)(N + 1) * 32 * 4);
    unsigned* bucketed = (unsigned*)p; p += align16((size_t)NB * CAPB * 4);
    unsigned short* csr = (unsigned short*)p; p += align16((size_t)E * 2);
    unsigned short* pcsr = (unsigned short*)p; p += align16((size_t)NB * 8192 * 2);
    int* gcur          = (int*)p; p += align16((size_t)(NB + 1) * 4);
    int* gstart        = (int*)p; p += align16((size_t)(NB + 1) * 4);
    int* rowptr        = (int*)p; p += align16((size_t)(N + 1) * 4);
    float* ssinv       = (float*)p; p += align16((size_t)N * 4);
    float* t           = (float*)p; p += align16((size_t)N * 4);

    const int nb_w4 = (N + 3) / 4;
    const int nb_bkt = (E + 2047) / 2048;
    const int ptotal = L * 64 * 128;
    const int nb_lay = (N + 15) / 16;

    k_setup<<<(ptotal + 255) / 256, 256, 0, stream>>>(ptotal, W_mid, WTh, NB, gcur, N, xAP, xBP);
    k_bucket<<<nb_bkt, 1024, 0, stream>>>(E, src, dst, gcur, bucketed, NB);
    k_bktscan<<<1, 512, 0, stream>>>(NB, N, gcur, gstart, rowptr);
    k_csr<<<NB, 256, 0, stream>>>(N, bucketed, gcur, gstart, csr, pcsr, rowptr, ssinv);

    k_in<<<nb_w4, 256, 0, stream>>>(N, x0, rowptr, csr, ssinv, W_in, b_in, xAP);

    for (int l = 0; l < L / 2; ++l) {
        bool last = (l == L / 2 - 1);
        const unsigned short* Wa = WTh + (size_t)(2 * l) * 64 * 128;
        const unsigned short* Wb = WTh + (size_t)(2 * l + 1) * 64 * 128;
        const float* W3a = W_mid + (size_t)(2 * l) * 129 * 64 + 128 * 64;
        const float* W3b = W_mid + (size_t)(2 * l + 1) * 129 * 64 + 128 * 64;

        // x1 = leaky(conv(x2)) : xAP -> xBP
        k_layer<false, false><<<nb_lay, 256, 0, stream>>>(
            N, xAP, nullptr, xBP, rowptr, csr, pcsr, ssinv,
            Wa, W3a, b_mid + (size_t)(2 * l) * HDIM, nullptr, nullptr);
        // x2 = leaky(conv(x1) + x2) : xBP (+xAP) -> xAP   [+ t on last]
        if (!last) {
            k_layer<true, false><<<nb_lay, 256, 0, stream>>>(
                N, xBP, xAP, xAP, rowptr, csr, pcsr, ssinv,
                Wb, W3b, b_mid + (size_t)(2 * l + 1) * HDIM, nullptr, nullptr);
        } else {
            k_layer<true, true><<<nb_lay, 256, 0, stream>>>(
                N, xBP, xAP, xAP, rowptr, csr, pcsr, ssinv,
                Wb, W3b, b_mid + (size_t)(2 * l + 1) * HDIM, W_out + 64, t);
        }
    }

    k_out<<<nb_w4, 256, 0, stream>>>(N, xAP, x0, rowptr, csr, ssinv, t,
                                     W_out, b_out, out);
}